// Round 1
// baseline (782.481 us; speedup 1.0000x reference)
//
#include <hip/hip_runtime.h>
#include <cstdint>
#include <cstddef>

// Problem constants (B=2,S=2048 -> T=4096; D=1024; H=4096; E=8; top-k=2)
#define T_TOK 4096
#define DIM   1024
#define HID   4096
#define NE    8
#define PAD   128
#define PADMAX 9216   // sum_e ceil(cnt_e/128)*128 <= 8192 + 8*127 = 9208 -> 9216

typedef _Float16 half_t;
typedef __attribute__((ext_vector_type(8))) _Float16 half8;
typedef __attribute__((ext_vector_type(4))) float floatx4;

__device__ __forceinline__ float silu_f(float v) {
  return v / (1.0f + expf(-v));
}

__device__ __forceinline__ half8 cvt44(float4 a, float4 b) {
  half8 o;
  o[0] = (half_t)a.x; o[1] = (half_t)a.y; o[2] = (half_t)a.z; o[3] = (half_t)a.w;
  o[4] = (half_t)b.x; o[5] = (half_t)b.y; o[6] = (half_t)b.z; o[7] = (half_t)b.w;
  return o;
}

// ---------------------------------------------------------------- reset
__global__ void k_reset(float* prob_sum, unsigned* cnt, unsigned* cursor,
                        int* pair_tok, float* pair_wt) {
  int i = blockIdx.x * 256 + threadIdx.x;
  if (i < PADMAX) { pair_tok[i] = 0; pair_wt[i] = 0.0f; }
  if (i < NE) { prob_sum[i] = 0.0f; cnt[i] = 0u; cursor[i] = 0u; }
}

// ---------------------------------------------------------------- W1 [E][D][H] -> W1t [E][Hc][D] f16
__global__ __launch_bounds__(256) void k_tr_w1(const float* __restrict__ W1,
                                               half_t* __restrict__ W1t,
                                               int j0, int Hc) {
  __shared__ half_t T[64][72];
  int e = blockIdx.z, h0 = blockIdx.x * 64, d0 = blockIdx.y * 64;
  int tid = threadIdx.x;
  {
    int r = tid >> 2, c16 = (tid & 3) * 16;
    const float* s = W1 + ((size_t)e * DIM + d0 + r) * HID + j0 + h0 + c16;
    float4 a = ((const float4*)s)[0], b = ((const float4*)s)[1];
    float4 c = ((const float4*)s)[2], d = ((const float4*)s)[3];
    *(half8*)&T[r][c16] = cvt44(a, b);
    *(half8*)&T[r][c16 + 8] = cvt44(c, d);
  }
  __syncthreads();
  {
    int n = tid >> 2, d16 = (tid & 3) * 16;
    half8 u, v;
#pragma unroll
    for (int j = 0; j < 8; ++j) { u[j] = T[d16 + j][n]; v[j] = T[d16 + 8 + j][n]; }
    half_t* dst = W1t + ((size_t)e * Hc + h0 + n) * DIM + d0 + d16;
    *(half8*)dst = u;
    *(half8*)(dst + 8) = v;
  }
}

// ---------------------------------------------------------------- W2 [E][H][D] -> W2t [E][D][Hc] f16
__global__ __launch_bounds__(256) void k_tr_w2(const float* __restrict__ W2,
                                               half_t* __restrict__ W2t,
                                               int j0, int Hc) {
  __shared__ half_t T[64][72];
  int e = blockIdx.z, d0 = blockIdx.x * 64, h0 = blockIdx.y * 64;
  int tid = threadIdx.x;
  {
    int r = tid >> 2, c16 = (tid & 3) * 16;
    const float* s = W2 + ((size_t)e * HID + j0 + h0 + r) * DIM + d0 + c16;
    float4 a = ((const float4*)s)[0], b = ((const float4*)s)[1];
    float4 c = ((const float4*)s)[2], d = ((const float4*)s)[3];
    *(half8*)&T[r][c16] = cvt44(a, b);
    *(half8*)&T[r][c16 + 8] = cvt44(c, d);
  }
  __syncthreads();
  {
    int n = tid >> 2, h16 = (tid & 3) * 16;
    half8 u, v;
#pragma unroll
    for (int j = 0; j < 8; ++j) { u[j] = T[h16 + j][n]; v[j] = T[h16 + 8 + j][n]; }
    half_t* dst = W2t + ((size_t)e * DIM + d0 + n) * Hc + h0 + h16;
    *(half8*)dst = u;
    *(half8*)(dst + 8) = v;
  }
}

// ---------------------------------------------------------------- router
__global__ __launch_bounds__(256) void k_router(
    const float* __restrict__ x, const float* __restrict__ Wg,
    int* __restrict__ top_i, float* __restrict__ top_w,
    float* __restrict__ prob_sum, unsigned* __restrict__ cnt) {
  __shared__ float sWg[NE * DIM];
  __shared__ float sProb[NE];
  __shared__ unsigned sCnt[NE];
  int tid = threadIdx.x;
  if (tid < NE) { sProb[tid] = 0.0f; sCnt[tid] = 0u; }
  for (int i = tid; i < NE * DIM; i += 256) sWg[i] = Wg[i];
  __syncthreads();

  int wave = tid >> 6, lane = tid & 63;
  for (int it = 0; it < 4; ++it) {
    int t = blockIdx.x * 16 + wave * 4 + it;
    const float* xp = x + (size_t)t * DIM;
    float acc[NE];
#pragma unroll
    for (int e = 0; e < NE; ++e) acc[e] = 0.0f;
    for (int i = 0; i < DIM / 64; ++i) {
      int d = i * 64 + lane;
      float xd = xp[d];
#pragma unroll
      for (int e = 0; e < NE; ++e) acc[e] = fmaf(xd, sWg[e * DIM + d], acc[e]);
    }
#pragma unroll
    for (int off = 32; off > 0; off >>= 1)
#pragma unroll
      for (int e = 0; e < NE; ++e) acc[e] += __shfl_xor(acc[e], off, 64);

    if (lane == 0) {
      float m = acc[0];
#pragma unroll
      for (int e = 1; e < NE; ++e) m = fmaxf(m, acc[e]);
      float pr[NE]; float s = 0.0f;
#pragma unroll
      for (int e = 0; e < NE; ++e) { pr[e] = expf(acc[e] - m); s += pr[e]; }
      float inv = 1.0f / s;
#pragma unroll
      for (int e = 0; e < NE; ++e) pr[e] *= inv;
      int i0 = 0; float v0 = pr[0];
#pragma unroll
      for (int e = 1; e < NE; ++e) if (pr[e] > v0) { v0 = pr[e]; i0 = e; }
      int i1 = -1; float v1 = -1.0f;
#pragma unroll
      for (int e = 0; e < NE; ++e) if (e != i0 && pr[e] > v1) { v1 = pr[e]; i1 = e; }
      float wn = 1.0f / (v0 + v1);
      top_i[t * 2 + 0] = i0; top_i[t * 2 + 1] = i1;
      top_w[t * 2 + 0] = v0 * wn; top_w[t * 2 + 1] = v1 * wn;
#pragma unroll
      for (int e = 0; e < NE; ++e) atomicAdd(&sProb[e], pr[e]);
      atomicAdd(&sCnt[i0], 1u);
      atomicAdd(&sCnt[i1], 1u);
    }
  }
  __syncthreads();
  if (tid < NE) {
    atomicAdd(&prob_sum[tid], sProb[tid]);
    atomicAdd(&cnt[tid], sCnt[tid]);
  }
}

// ---------------------------------------------------------------- scan + aux loss
__global__ void k_scan(const unsigned* __restrict__ cnt,
                       const float* __restrict__ prob_sum,
                       int* __restrict__ pad_off, int* __restrict__ ptotal,
                       float* __restrict__ aux_out) {
  if (threadIdx.x == 0 && blockIdx.x == 0) {
    int off = 0; float aux = 0.0f;
    for (int e = 0; e < NE; ++e) {
      pad_off[e] = off;
      off += (int)((cnt[e] + (PAD - 1u)) & ~(unsigned)(PAD - 1));
      aux += ((float)cnt[e] / (float)T_TOK) * (prob_sum[e] / (float)T_TOK);
    }
    pad_off[NE] = off;
    *ptotal = off;
    *aux_out = (float)NE * aux;
  }
}

// ---------------------------------------------------------------- scatter pairs
__global__ void k_scatter(const int* __restrict__ top_i, const float* __restrict__ top_w,
                          const int* __restrict__ pad_off, unsigned* __restrict__ cursor,
                          int* __restrict__ pair_tok, float* __restrict__ pair_wt) {
  int t = blockIdx.x * 256 + threadIdx.x;
  if (t >= T_TOK) return;
#pragma unroll
  for (int k = 0; k < 2; ++k) {
    int e = top_i[t * 2 + k];
    unsigned pos = atomicAdd(&cursor[e], 1u);
    int idx = pad_off[e] + (int)pos;
    pair_tok[idx] = t;
    pair_wt[idx]  = top_w[t * 2 + k];
  }
}

// ---------------------------------------------------------------- out = w0*b2[e0] + w1*b2[e1]
__global__ void k_init_out(const int* __restrict__ top_i, const float* __restrict__ top_w,
                           const float* __restrict__ b2, float* __restrict__ out) {
  int idx = blockIdx.x * 256 + threadIdx.x;
  int t = idx >> 10, d = idx & (DIM - 1);
  int e0 = top_i[t * 2 + 0], e1 = top_i[t * 2 + 1];
  out[idx] = top_w[t * 2 + 0] * b2[e0 * DIM + d] + top_w[t * 2 + 1] * b2[e1 * DIM + d];
}

// ================================================================ Mode A GEMM1 (f16 transposed weights)
__global__ __launch_bounds__(256) void k_gemm1_a(
    const float* __restrict__ x, const half_t* __restrict__ W1t,
    const float* __restrict__ b1, const int* __restrict__ pair_tok,
    const int* __restrict__ pad_off, const int* __restrict__ ptotal,
    half_t* __restrict__ hout, int j0, int Hc) {
  __shared__ half_t lds[16384];
  int P = *ptotal;
  int p0 = blockIdx.y * 128;
  if (p0 >= P) return;
  int e = 0;
#pragma unroll
  for (int q = 1; q < NE; ++q) if (p0 >= pad_off[q]) e = q;

  int tid = threadIdx.x, w = tid >> 6, l = tid & 63;
  int lr = l & 15, lq = l >> 4;
  int wr = w >> 1, wc = w & 1;
  int jt = blockIdx.x * 128;

  int tok0 = pair_tok[p0 + (2 * w) * 16 + lr];
  int tok1 = pair_tok[p0 + (2 * w + 1) * 16 + lr];
  const float* gA0 = x + (size_t)tok0 * DIM + lq * 8;
  const float* gA1 = x + (size_t)tok1 * DIM + lq * 8;
  const half_t* gB0 = W1t + ((size_t)e * Hc + jt + (2 * w) * 16 + lr) * DIM + lq * 8;
  const half_t* gB1 = W1t + ((size_t)e * Hc + jt + (2 * w + 1) * 16 + lr) * DIM + lq * 8;

  half_t* ldsA = lds;
  half_t* ldsB = lds + 8192;

  floatx4 acc[4][4];
#pragma unroll
  for (int i = 0; i < 4; ++i)
#pragma unroll
    for (int j = 0; j < 4; ++j) acc[i][j] = (floatx4){0.f, 0.f, 0.f, 0.f};

  for (int kt = 0; kt < DIM; kt += 64) {
    half8 va0 = cvt44(*(const float4*)(gA0 + kt),      *(const float4*)(gA0 + kt + 4));
    half8 va1 = cvt44(*(const float4*)(gA0 + kt + 32), *(const float4*)(gA0 + kt + 36));
    half8 va2 = cvt44(*(const float4*)(gA1 + kt),      *(const float4*)(gA1 + kt + 4));
    half8 va3 = cvt44(*(const float4*)(gA1 + kt + 32), *(const float4*)(gA1 + kt + 36));
    half8 vb0 = *(const half8*)(gB0 + kt);
    half8 vb1 = *(const half8*)(gB0 + kt + 32);
    half8 vb2 = *(const half8*)(gB1 + kt);
    half8 vb3 = *(const half8*)(gB1 + kt + 32);
    __syncthreads();
    *(half8*)(ldsA + (4 * w + 0) * 512 + l * 8) = va0;
    *(half8*)(ldsA + (4 * w + 1) * 512 + l * 8) = va1;
    *(half8*)(ldsA + (4 * w + 2) * 512 + l * 8) = va2;
    *(half8*)(ldsA + (4 * w + 3) * 512 + l * 8) = va3;
    *(half8*)(ldsB + (4 * w + 0) * 512 + l * 8) = vb0;
    *(half8*)(ldsB + (4 * w + 1) * 512 + l * 8) = vb1;
    *(half8*)(ldsB + (4 * w + 2) * 512 + l * 8) = vb2;
    *(half8*)(ldsB + (4 * w + 3) * 512 + l * 8) = vb3;
    __syncthreads();
#pragma unroll
    for (int ks = 0; ks < 2; ++ks) {
      half8 a[4], b[4];
#pragma unroll
      for (int i = 0; i < 4; ++i)
        a[i] = *(const half8*)(ldsA + ((4 * wr + i) * 2 + ks) * 512 + l * 8);
#pragma unroll
      for (int j = 0; j < 4; ++j)
        b[j] = *(const half8*)(ldsB + ((4 * wc + j) * 2 + ks) * 512 + l * 8);
#pragma unroll
      for (int i = 0; i < 4; ++i)
#pragma unroll
        for (int j = 0; j < 4; ++j)
          acc[i][j] = __builtin_amdgcn_mfma_f32_16x16x32_f16(a[i], b[j], acc[i][j], 0, 0, 0);
    }
  }
  __syncthreads();

#pragma unroll
  for (int j = 0; j < 4; ++j) {
    int coll = (4 * wc + j) * 16 + lr;
    float bias = b1[(size_t)e * HID + j0 + jt + coll];
#pragma unroll
    for (int i = 0; i < 4; ++i)
#pragma unroll
      for (int r = 0; r < 4; ++r) {
        int row = (4 * wr + i) * 16 + lq * 4 + r;
        lds[row * 128 + coll] = (half_t)silu_f(acc[i][j][r] + bias);
      }
  }
  __syncthreads();
  // FIXED: each thread stores 16 halves (two half8) to cover all 128 columns.
#pragma unroll
  for (int ps = 0; ps < 4; ++ps) {
    int r = ps * 32 + (tid >> 3), c = (tid & 7) * 16;
    half8 v0 = *(const half8*)(lds + r * 128 + c);
    half8 v1 = *(const half8*)(lds + r * 128 + c + 8);
    half_t* dst = hout + (size_t)(p0 + r) * Hc + jt + c;
    *(half8*)dst = v0;
    *(half8*)(dst + 8) = v1;
  }
}

// ================================================================ Mode A GEMM2
__global__ __launch_bounds__(256) void k_gemm2_a(
    const half_t* __restrict__ hbuf, const half_t* __restrict__ W2t,
    const int* __restrict__ pair_tok, const float* __restrict__ pair_wt,
    const int* __restrict__ pad_off, const int* __restrict__ ptotal,
    float* __restrict__ out, int Hc) {
  __shared__ half_t lds[16384];
  int P = *ptotal;
  int p0 = blockIdx.y * 128;
  if (p0 >= P) return;
  int e = 0;
#pragma unroll
  for (int q = 1; q < NE; ++q) if (p0 >= pad_off[q]) e = q;

  int tid = threadIdx.x, w = tid >> 6, l = tid & 63;
  int lr = l & 15, lq = l >> 4;
  int wr = w >> 1, wc = w & 1;
  int jt = blockIdx.x * 128;

  const half_t* gA0 = hbuf + (size_t)(p0 + (2 * w) * 16 + lr) * Hc + lq * 8;
  const half_t* gA1 = hbuf + (size_t)(p0 + (2 * w + 1) * 16 + lr) * Hc + lq * 8;
  const half_t* gB0 = W2t + ((size_t)e * DIM + jt + (2 * w) * 16 + lr) * Hc + lq * 8;
  const half_t* gB1 = W2t + ((size_t)e * DIM + jt + (2 * w + 1) * 16 + lr) * Hc + lq * 8;

  half_t* ldsA = lds;
  half_t* ldsB = lds + 8192;

  floatx4 acc[4][4];
#pragma unroll
  for (int i = 0; i < 4; ++i)
#pragma unroll
    for (int j = 0; j < 4; ++j) acc[i][j] = (floatx4){0.f, 0.f, 0.f, 0.f};

  for (int kt = 0; kt < Hc; kt += 64) {
    half8 va0 = *(const half8*)(gA0 + kt);
    half8 va1 = *(const half8*)(gA0 + kt + 32);
    half8 va2 = *(const half8*)(gA1 + kt);
    half8 va3 = *(const half8*)(gA1 + kt + 32);
    half8 vb0 = *(const half8*)(gB0 + kt);
    half8 vb1 = *(const half8*)(gB0 + kt + 32);
    half8 vb2 = *(const half8*)(gB1 + kt);
    half8 vb3 = *(const half8*)(gB1 + kt + 32);
    __syncthreads();
    *(half8*)(ldsA + (4 * w + 0) * 512 + l * 8) = va0;
    *(half8*)(ldsA + (4 * w + 1) * 512 + l * 8) = va1;
    *(half8*)(ldsA + (4 * w + 2) * 512 + l * 8) = va2;
    *(half8*)(ldsA + (4 * w + 3) * 512 + l * 8) = va3;
    *(half8*)(ldsB + (4 * w + 0) * 512 + l * 8) = vb0;
    *(half8*)(ldsB + (4 * w + 1) * 512 + l * 8) = vb1;
    *(half8*)(ldsB + (4 * w + 2) * 512 + l * 8) = vb2;
    *(half8*)(ldsB + (4 * w + 3) * 512 + l * 8) = vb3;
    __syncthreads();
#pragma unroll
    for (int ks = 0; ks < 2; ++ks) {
      half8 a[4], b[4];
#pragma unroll
      for (int i = 0; i < 4; ++i)
        a[i] = *(const half8*)(ldsA + ((4 * wr + i) * 2 + ks) * 512 + l * 8);
#pragma unroll
      for (int j = 0; j < 4; ++j)
        b[j] = *(const half8*)(ldsB + ((4 * wc + j) * 2 + ks) * 512 + l * 8);
#pragma unroll
      for (int i = 0; i < 4; ++i)
#pragma unroll
        for (int j = 0; j < 4; ++j)
          acc[i][j] = __builtin_amdgcn_mfma_f32_16x16x32_f16(a[i], b[j], acc[i][j], 0, 0, 0);
    }
  }

#pragma unroll
  for (int i = 0; i < 4; ++i)
#pragma unroll
    for (int r = 0; r < 4; ++r) {
      int row = (4 * wr + i) * 16 + lq * 4 + r;
      float wt = pair_wt[p0 + row];
      if (wt != 0.0f) {
        int tok = pair_tok[p0 + row];
        float* op = out + (size_t)tok * DIM + jt;
#pragma unroll
        for (int j = 0; j < 4; ++j) {
          int coll = (4 * wc + j) * 16 + lr;
          unsafeAtomicAdd(op + coll, wt * acc[i][j][r]);
        }
      }
    }
}

// ================================================================ Mode B GEMM1 (fp32 weights direct)
__global__ __launch_bounds__(256) void k_gemm1_b(
    const float* __restrict__ x, const float* __restrict__ W1,
    const float* __restrict__ b1, const int* __restrict__ pair_tok,
    const int* __restrict__ pad_off, const int* __restrict__ ptotal,
    half_t* __restrict__ hout, int j0, int Hc) {
  __shared__ half_t lds[16384];
  int P = *ptotal;
  int p0 = blockIdx.y * 128;
  if (p0 >= P) return;
  int e = 0;
#pragma unroll
  for (int q = 1; q < NE; ++q) if (p0 >= pad_off[q]) e = q;

  int tid = threadIdx.x, w = tid >> 6, l = tid & 63;
  int lr = l & 15, lq = l >> 4;
  int wr = w >> 1, wc = w & 1;
  int jt = blockIdx.x * 128;

  int tok0 = pair_tok[p0 + (2 * w) * 16 + lr];
  int tok1 = pair_tok[p0 + (2 * w + 1) * 16 + lr];
  const float* gA0 = x + (size_t)tok0 * DIM + lq * 8;
  const float* gA1 = x + (size_t)tok1 * DIM + lq * 8;
  const float* gBb = W1 + (size_t)e * DIM * HID + j0 + jt;
  const float* gB0 = gBb + (2 * w) * 16 + lr;
  const float* gB1 = gBb + (2 * w + 1) * 16 + lr;

  half_t* ldsA = lds;
  half_t* ldsB = lds + 8192;

  floatx4 acc[4][4];
#pragma unroll
  for (int i = 0; i < 4; ++i)
#pragma unroll
    for (int j = 0; j < 4; ++j) acc[i][j] = (floatx4){0.f, 0.f, 0.f, 0.f};

  for (int kt = 0; kt < DIM; kt += 64) {
    half8 va0 = cvt44(*(const float4*)(gA0 + kt),      *(const float4*)(gA0 + kt + 4));
    half8 va1 = cvt44(*(const float4*)(gA0 + kt + 32), *(const float4*)(gA0 + kt + 36));
    half8 va2 = cvt44(*(const float4*)(gA1 + kt),      *(const float4*)(gA1 + kt + 4));
    half8 va3 = cvt44(*(const float4*)(gA1 + kt + 32), *(const float4*)(gA1 + kt + 36));
    half8 vb[4];
#pragma unroll
    for (int fg = 0; fg < 4; ++fg) {
      const float* gb = (fg >> 1) ? gB1 : gB0;
      int kbase = kt + (fg & 1) * 32 + lq * 8;
#pragma unroll
      for (int j = 0; j < 8; ++j)
        vb[fg][j] = (half_t)gb[(size_t)(kbase + j) * HID];
    }
    __syncthreads();
    *(half8*)(ldsA + (4 * w + 0) * 512 + l * 8) = va0;
    *(half8*)(ldsA + (4 * w + 1) * 512 + l * 8) = va1;
    *(half8*)(ldsA + (4 * w + 2) * 512 + l * 8) = va2;
    *(half8*)(ldsA + (4 * w + 3) * 512 + l * 8) = va3;
    *(half8*)(ldsB + (4 * w + 0) * 512 + l * 8) = vb[0];
    *(half8*)(ldsB + (4 * w + 1) * 512 + l * 8) = vb[1];
    *(half8*)(ldsB + (4 * w + 2) * 512 + l * 8) = vb[2];
    *(half8*)(ldsB + (4 * w + 3) * 512 + l * 8) = vb[3];
    __syncthreads();
#pragma unroll
    for (int ks = 0; ks < 2; ++ks) {
      half8 a[4], b[4];
#pragma unroll
      for (int i = 0; i < 4; ++i)
        a[i] = *(const half8*)(ldsA + ((4 * wr + i) * 2 + ks) * 512 + l * 8);
#pragma unroll
      for (int j = 0; j < 4; ++j)
        b[j] = *(const half8*)(ldsB + ((4 * wc + j) * 2 + ks) * 512 + l * 8);
#pragma unroll
      for (int i = 0; i < 4; ++i)
#pragma unroll
        for (int j = 0; j < 4; ++j)
          acc[i][j] = __builtin_amdgcn_mfma_f32_16x16x32_f16(a[i], b[j], acc[i][j], 0, 0, 0);
    }
  }
  __syncthreads();

#pragma unroll
  for (int j = 0; j < 4; ++j) {
    int coll = (4 * wc + j) * 16 + lr;
    float bias = b1[(size_t)e * HID + j0 + jt + coll];
#pragma unroll
    for (int i = 0; i < 4; ++i)
#pragma unroll
      for (int r = 0; r < 4; ++r) {
        int row = (4 * wr + i) * 16 + lq * 4 + r;
        lds[row * 128 + coll] = (half_t)silu_f(acc[i][j][r] + bias);
      }
  }
  __syncthreads();
  // FIXED: two half8 per thread.
#pragma unroll
  for (int ps = 0; ps < 4; ++ps) {
    int r = ps * 32 + (tid >> 3), c = (tid & 7) * 16;
    half8 v0 = *(const half8*)(lds + r * 128 + c);
    half8 v1 = *(const half8*)(lds + r * 128 + c + 8);
    half_t* dst = hout + (size_t)(p0 + r) * Hc + jt + c;
    *(half8*)dst = v0;
    *(half8*)(dst + 8) = v1;
  }
}

// ================================================================ Mode B GEMM2 (fp32 W2 direct)
__global__ __launch_bounds__(256) void k_gemm2_b(
    const half_t* __restrict__ hbuf, const float* __restrict__ W2,
    const int* __restrict__ pair_tok, const float* __restrict__ pair_wt,
    const int* __restrict__ pad_off, const int* __restrict__ ptotal,
    float* __restrict__ out, int j0, int Hc) {
  __shared__ half_t lds[16384];
  int P = *ptotal;
  int p0 = blockIdx.y * 128;
  if (p0 >= P) return;
  int e = 0;
#pragma unroll
  for (int q = 1; q < NE; ++q) if (p0 >= pad_off[q]) e = q;

  int tid = threadIdx.x, w = tid >> 6, l = tid & 63;
  int lr = l & 15, lq = l >> 4;
  int wr = w >> 1, wc = w & 1;
  int jt = blockIdx.x * 128;

  const half_t* gA0 = hbuf + (size_t)(p0 + (2 * w) * 16 + lr) * Hc + lq * 8;
  const half_t* gA1 = hbuf + (size_t)(p0 + (2 * w + 1) * 16 + lr) * Hc + lq * 8;
  const float* gBb = W2 + (size_t)e * HID * DIM + jt;
  const float* gB0 = gBb + (2 * w) * 16 + lr;
  const float* gB1 = gBb + (2 * w + 1) * 16 + lr;

  half_t* ldsA = lds;
  half_t* ldsB = lds + 8192;

  floatx4 acc[4][4];
#pragma unroll
  for (int i = 0; i < 4; ++i)
#pragma unroll
    for (int j = 0; j < 4; ++j) acc[i][j] = (floatx4){0.f, 0.f, 0.f, 0.f};

  for (int kt = 0; kt < Hc; kt += 64) {
    half8 va0 = *(const half8*)(gA0 + kt);
    half8 va1 = *(const half8*)(gA0 + kt + 32);
    half8 va2 = *(const half8*)(gA1 + kt);
    half8 va3 = *(const half8*)(gA1 + kt + 32);
    half8 vb[4];
#pragma unroll
    for (int fg = 0; fg < 4; ++fg) {
      const float* gb = (fg >> 1) ? gB1 : gB0;
      int kbase = j0 + kt + (fg & 1) * 32 + lq * 8;
#pragma unroll
      for (int j = 0; j < 8; ++j)
        vb[fg][j] = (half_t)gb[(size_t)(kbase + j) * DIM];
    }
    __syncthreads();
    *(half8*)(ldsA + (4 * w + 0) * 512 + l * 8) = va0;
    *(half8*)(ldsA + (4 * w + 1) * 512 + l * 8) = va1;
    *(half8*)(ldsA + (4 * w + 2) * 512 + l * 8) = va2;
    *(half8*)(ldsA + (4 * w + 3) * 512 + l * 8) = va3;
    *(half8*)(ldsB + (4 * w + 0) * 512 + l * 8) = vb[0];
    *(half8*)(ldsB + (4 * w + 1) * 512 + l * 8) = vb[1];
    *(half8*)(ldsB + (4 * w + 2) * 512 + l * 8) = vb[2];
    *(half8*)(ldsB + (4 * w + 3) * 512 + l * 8) = vb[3];
    __syncthreads();
#pragma unroll
    for (int ks = 0; ks < 2; ++ks) {
      half8 a[4], b[4];
#pragma unroll
      for (int i = 0; i < 4; ++i)
        a[i] = *(const half8*)(ldsA + ((4 * wr + i) * 2 + ks) * 512 + l * 8);
#pragma unroll
      for (int j = 0; j < 4; ++j)
        b[j] = *(const half8*)(ldsB + ((4 * wc + j) * 2 + ks) * 512 + l * 8);
#pragma unroll
      for (int i = 0; i < 4; ++i)
#pragma unroll
        for (int j = 0; j < 4; ++j)
          acc[i][j] = __builtin_amdgcn_mfma_f32_16x16x32_f16(a[i], b[j], acc[i][j], 0, 0, 0);
    }
  }

#pragma unroll
  for (int i = 0; i < 4; ++i)
#pragma unroll
    for (int r = 0; r < 4; ++r) {
      int row = (4 * wr + i) * 16 + lq * 4 + r;
      float wt = pair_wt[p0 + row];
      if (wt != 0.0f) {
        int tok = pair_tok[p0 + row];
        float* op = out + (size_t)tok * DIM + jt;
#pragma unroll
        for (int j = 0; j < 4; ++j) {
          int coll = (4 * wc + j) * 16 + lr;
          unsafeAtomicAdd(op + coll, wt * acc[i][j][r]);
        }
      }
    }
}

// ---------------------------------------------------------------- launch
extern "C" void kernel_launch(void* const* d_in, const int* in_sizes, int n_in,
                              void* d_out, int out_size, void* d_ws, size_t ws_size,
                              hipStream_t stream) {
  const float* x  = (const float*)d_in[0];
  const float* Wg = (const float*)d_in[1];
  const float* W1 = (const float*)d_in[2];
  const float* b1 = (const float*)d_in[3];
  const float* W2 = (const float*)d_in[4];
  const float* b2 = (const float*)d_in[5];
  float* out = (float*)d_out;

  char* p = (char*)d_ws;
  auto alloc = [&](size_t bytes) -> char* {
    char* r = p; p += (bytes + 255) & ~(size_t)255; return r;
  };
  int*      top_i    = (int*)     alloc((size_t)T_TOK * 2 * sizeof(int));
  float*    top_w    = (float*)   alloc((size_t)T_TOK * 2 * sizeof(float));
  float*    prob_sum = (float*)   alloc(NE * sizeof(float));
  unsigned* cnt      = (unsigned*)alloc(NE * sizeof(unsigned));
  int*      pad_off  = (int*)     alloc((NE + 1) * sizeof(int));
  int*      ptotal   = (int*)     alloc(sizeof(int));
  unsigned* cursor   = (unsigned*)alloc(NE * sizeof(unsigned));
  int*      pair_tok = (int*)     alloc(PADMAX * sizeof(int));
  float*    pair_wt  = (float*)   alloc(PADMAX * sizeof(float));

  size_t used  = (size_t)(p - (char*)d_ws);          // ~140 KB fixed
  size_t avail = ws_size > used ? ws_size - used : 0;

  // Mode A per-H-column cost: W1t + W2t (2*NE*DIM*2B) + hbuf (PADMAX*2B) = 51200 B
  size_t per_col_a = (size_t)2 * NE * DIM * sizeof(half_t) + (size_t)PADMAX * sizeof(half_t);
  int HcA = (int)((avail / per_col_a) & ~(size_t)127);
  if (HcA > HID) HcA = HID;
  bool modeA = (HcA >= 128);

  k_reset<<<dim3((PADMAX + 255) / 256), 256, 0, stream>>>(prob_sum, cnt, cursor, pair_tok, pair_wt);
  k_router<<<dim3(T_TOK / 16), 256, 0, stream>>>(x, Wg, top_i, top_w, prob_sum, cnt);
  k_scan<<<1, 64, 0, stream>>>(cnt, prob_sum, pad_off, ptotal, out + (size_t)T_TOK * DIM);
  k_scatter<<<dim3(T_TOK / 256), 256, 0, stream>>>(top_i, top_w, pad_off, cursor, pair_tok, pair_wt);
  k_init_out<<<dim3((size_t)T_TOK * DIM / 256), 256, 0, stream>>>(top_i, top_w, b2, out);

  if (modeA) {
    int Hc = HcA;
    half_t* W1t  = (half_t*)alloc((size_t)NE * Hc * DIM * sizeof(half_t));
    half_t* W2t  = (half_t*)alloc((size_t)NE * DIM * Hc * sizeof(half_t));
    half_t* hbuf = (half_t*)alloc((size_t)PADMAX * Hc * sizeof(half_t));
    for (int jb = 0; jb < HID; jb += Hc) {
      int hc = (HID - jb) < Hc ? (HID - jb) : Hc;   // multiple of 128
      k_tr_w1<<<dim3(hc / 64, DIM / 64, NE), 256, 0, stream>>>(W1, W1t, jb, hc);
      k_gemm1_a<<<dim3(hc / 128, PADMAX / 128), 256, 0, stream>>>(
          x, W1t, b1, pair_tok, pad_off, ptotal, hbuf, jb, hc);
      k_tr_w2<<<dim3(DIM / 64, hc / 64, NE), 256, 0, stream>>>(W2, W2t, jb, hc);
      k_gemm2_a<<<dim3(DIM / 128, PADMAX / 128), 256, 0, stream>>>(
          hbuf, W2t, pair_tok, pair_wt, pad_off, ptotal, out, hc);
    }
  } else {
    // Mode B: only hbuf, fp32 weights read directly in the GEMMs.
    int Hc = (int)((avail / ((size_t)PADMAX * sizeof(half_t))) & ~(size_t)127);
    if (Hc > HID) Hc = HID;
    if (Hc < 128) Hc = 128;   // ~2.4 MB floor (R1 passed with this footprint)
    half_t* hbuf = (half_t*)alloc((size_t)PADMAX * Hc * sizeof(half_t));
    for (int jb = 0; jb < HID; jb += Hc) {
      int hc = (HID - jb) < Hc ? (HID - jb) : Hc;
      k_gemm1_b<<<dim3(hc / 128, PADMAX / 128), 256, 0, stream>>>(
          x, W1, b1, pair_tok, pad_off, ptotal, hbuf, jb, hc);
      k_gemm2_b<<<dim3(DIM / 128, PADMAX / 128), 256, 0, stream>>>(
          hbuf, W2, pair_tok, pair_wt, pad_off, ptotal, out, jb, hc);
    }
  }
}

// Round 2
// 756.813 us; speedup vs baseline: 1.0339x; 1.0339x over previous
//
#include <hip/hip_runtime.h>
#include <cstdint>
#include <cstddef>

// Problem constants (B=2,S=2048 -> T=4096; D=1024; H=4096; E=8; top-k=2)
#define T_TOK 4096
#define DIM   1024
#define HID   4096
#define NE    8
#define PAD   128
#define PADMAX 9216   // sum_e ceil(cnt_e/128)*128 <= 8192 + 8*127 = 9208 -> 9216

typedef _Float16 half_t;
typedef __attribute__((ext_vector_type(8))) _Float16 half8;
typedef __attribute__((ext_vector_type(4))) float floatx4;

__device__ __forceinline__ float silu_f(float v) {
  return v / (1.0f + expf(-v));
}

__device__ __forceinline__ half8 cvt44(float4 a, float4 b) {
  half8 o;
  o[0] = (half_t)a.x; o[1] = (half_t)a.y; o[2] = (half_t)a.z; o[3] = (half_t)a.w;
  o[4] = (half_t)b.x; o[5] = (half_t)b.y; o[6] = (half_t)b.z; o[7] = (half_t)b.w;
  return o;
}

// Async global->LDS, 16B per lane. LDS dest = wave-uniform base + lane*16B
// (m104/m108); global src addr is per-lane (gather OK). Data is guaranteed
// landed after __syncthreads() (compiler drains vmcnt(0) before s_barrier).
__device__ __forceinline__ void gload16(const void* g, void* l) {
  __builtin_amdgcn_global_load_lds(
      (const __attribute__((address_space(1))) unsigned int*)g,
      (__attribute__((address_space(3))) unsigned int*)l, 16, 0, 0);
}

// ---------------------------------------------------------------- reset
__global__ void k_reset(float* prob_sum, unsigned* cnt, unsigned* cursor,
                        int* pair_tok, float* pair_wt) {
  int i = blockIdx.x * 256 + threadIdx.x;
  if (i < PADMAX) { pair_tok[i] = 0; pair_wt[i] = 0.0f; }
  if (i < NE) { prob_sum[i] = 0.0f; cnt[i] = 0u; cursor[i] = 0u; }
}

// ---------------------------------------------------------------- x fp32 -> f16 (once)
__global__ __launch_bounds__(256) void k_cvt_x(const float* __restrict__ x,
                                               half_t* __restrict__ xh) {
  size_t i = (size_t)blockIdx.x * 256 + threadIdx.x;   // one half8 per thread
  const float4* s = (const float4*)(x + i * 8);
  float4 a = s[0], b = s[1];
  *(half8*)(xh + i * 8) = cvt44(a, b);
}

// ---------------------------------------------------------------- W1 [E][D][H] -> W1t [E][Hc][D] f16
__global__ __launch_bounds__(256) void k_tr_w1(const float* __restrict__ W1,
                                               half_t* __restrict__ W1t,
                                               int j0, int Hc) {
  __shared__ half_t T[64][72];
  int e = blockIdx.z, h0 = blockIdx.x * 64, d0 = blockIdx.y * 64;
  int tid = threadIdx.x;
  {
    int r = tid >> 2, c16 = (tid & 3) * 16;
    const float* s = W1 + ((size_t)e * DIM + d0 + r) * HID + j0 + h0 + c16;
    float4 a = ((const float4*)s)[0], b = ((const float4*)s)[1];
    float4 c = ((const float4*)s)[2], d = ((const float4*)s)[3];
    *(half8*)&T[r][c16] = cvt44(a, b);
    *(half8*)&T[r][c16 + 8] = cvt44(c, d);
  }
  __syncthreads();
  {
    int n = tid >> 2, d16 = (tid & 3) * 16;
    half8 u, v;
#pragma unroll
    for (int j = 0; j < 8; ++j) { u[j] = T[d16 + j][n]; v[j] = T[d16 + 8 + j][n]; }
    half_t* dst = W1t + ((size_t)e * Hc + h0 + n) * DIM + d0 + d16;
    *(half8*)dst = u;
    *(half8*)(dst + 8) = v;
  }
}

// ---------------------------------------------------------------- W2 [E][H][D] -> W2t [E][D][Hc] f16
__global__ __launch_bounds__(256) void k_tr_w2(const float* __restrict__ W2,
                                               half_t* __restrict__ W2t,
                                               int j0, int Hc) {
  __shared__ half_t T[64][72];
  int e = blockIdx.z, d0 = blockIdx.x * 64, h0 = blockIdx.y * 64;
  int tid = threadIdx.x;
  {
    int r = tid >> 2, c16 = (tid & 3) * 16;
    const float* s = W2 + ((size_t)e * HID + j0 + h0 + r) * DIM + d0 + c16;
    float4 a = ((const float4*)s)[0], b = ((const float4*)s)[1];
    float4 c = ((const float4*)s)[2], d = ((const float4*)s)[3];
    *(half8*)&T[r][c16] = cvt44(a, b);
    *(half8*)&T[r][c16 + 8] = cvt44(c, d);
  }
  __syncthreads();
  {
    int n = tid >> 2, h16 = (tid & 3) * 16;
    half8 u, v;
#pragma unroll
    for (int j = 0; j < 8; ++j) { u[j] = T[h16 + j][n]; v[j] = T[h16 + 8 + j][n]; }
    half_t* dst = W2t + ((size_t)e * DIM + d0 + n) * Hc + h0 + h16;
    *(half8*)dst = u;
    *(half8*)(dst + 8) = v;
  }
}

// ---------------------------------------------------------------- router
__global__ __launch_bounds__(256) void k_router(
    const float* __restrict__ x, const float* __restrict__ Wg,
    int* __restrict__ top_i, float* __restrict__ top_w,
    float* __restrict__ prob_sum, unsigned* __restrict__ cnt) {
  __shared__ float sWg[NE * DIM];
  __shared__ float sProb[NE];
  __shared__ unsigned sCnt[NE];
  int tid = threadIdx.x;
  if (tid < NE) { sProb[tid] = 0.0f; sCnt[tid] = 0u; }
  for (int i = tid; i < NE * DIM; i += 256) sWg[i] = Wg[i];
  __syncthreads();

  int wave = tid >> 6, lane = tid & 63;
  for (int it = 0; it < 4; ++it) {
    int t = blockIdx.x * 16 + wave * 4 + it;
    const float* xp = x + (size_t)t * DIM;
    float acc[NE];
#pragma unroll
    for (int e = 0; e < NE; ++e) acc[e] = 0.0f;
    for (int i = 0; i < DIM / 64; ++i) {
      int d = i * 64 + lane;
      float xd = xp[d];
#pragma unroll
      for (int e = 0; e < NE; ++e) acc[e] = fmaf(xd, sWg[e * DIM + d], acc[e]);
    }
#pragma unroll
    for (int off = 32; off > 0; off >>= 1)
#pragma unroll
      for (int e = 0; e < NE; ++e) acc[e] += __shfl_xor(acc[e], off, 64);

    if (lane == 0) {
      float m = acc[0];
#pragma unroll
      for (int e = 1; e < NE; ++e) m = fmaxf(m, acc[e]);
      float pr[NE]; float s = 0.0f;
#pragma unroll
      for (int e = 0; e < NE; ++e) { pr[e] = expf(acc[e] - m); s += pr[e]; }
      float inv = 1.0f / s;
#pragma unroll
      for (int e = 0; e < NE; ++e) pr[e] *= inv;
      int i0 = 0; float v0 = pr[0];
#pragma unroll
      for (int e = 1; e < NE; ++e) if (pr[e] > v0) { v0 = pr[e]; i0 = e; }
      int i1 = -1; float v1 = -1.0f;
#pragma unroll
      for (int e = 0; e < NE; ++e) if (e != i0 && pr[e] > v1) { v1 = pr[e]; i1 = e; }
      float wn = 1.0f / (v0 + v1);
      top_i[t * 2 + 0] = i0; top_i[t * 2 + 1] = i1;
      top_w[t * 2 + 0] = v0 * wn; top_w[t * 2 + 1] = v1 * wn;
#pragma unroll
      for (int e = 0; e < NE; ++e) atomicAdd(&sProb[e], pr[e]);
      atomicAdd(&sCnt[i0], 1u);
      atomicAdd(&sCnt[i1], 1u);
    }
  }
  __syncthreads();
  if (tid < NE) {
    atomicAdd(&prob_sum[tid], sProb[tid]);
    atomicAdd(&cnt[tid], sCnt[tid]);
  }
}

// ---------------------------------------------------------------- scan + aux loss
__global__ void k_scan(const unsigned* __restrict__ cnt,
                       const float* __restrict__ prob_sum,
                       int* __restrict__ pad_off, int* __restrict__ ptotal,
                       float* __restrict__ aux_out) {
  if (threadIdx.x == 0 && blockIdx.x == 0) {
    int off = 0; float aux = 0.0f;
    for (int e = 0; e < NE; ++e) {
      pad_off[e] = off;
      off += (int)((cnt[e] + (PAD - 1u)) & ~(unsigned)(PAD - 1));
      aux += ((float)cnt[e] / (float)T_TOK) * (prob_sum[e] / (float)T_TOK);
    }
    pad_off[NE] = off;
    *ptotal = off;
    *aux_out = (float)NE * aux;
  }
}

// ---------------------------------------------------------------- scatter pairs
__global__ void k_scatter(const int* __restrict__ top_i, const float* __restrict__ top_w,
                          const int* __restrict__ pad_off, unsigned* __restrict__ cursor,
                          int* __restrict__ pair_tok, float* __restrict__ pair_wt) {
  int t = blockIdx.x * 256 + threadIdx.x;
  if (t >= T_TOK) return;
#pragma unroll
  for (int k = 0; k < 2; ++k) {
    int e = top_i[t * 2 + k];
    unsigned pos = atomicAdd(&cursor[e], 1u);
    int idx = pad_off[e] + (int)pos;
    pair_tok[idx] = t;
    pair_wt[idx]  = top_w[t * 2 + k];
  }
}

// ---------------------------------------------------------------- out = w0*b2[e0] + w1*b2[e1]
__global__ void k_init_out(const int* __restrict__ top_i, const float* __restrict__ top_w,
                           const float* __restrict__ b2, float* __restrict__ out) {
  int idx = blockIdx.x * 256 + threadIdx.x;
  int t = idx >> 10, d = idx & (DIM - 1);
  int e0 = top_i[t * 2 + 0], e1 = top_i[t * 2 + 1];
  out[idx] = top_w[t * 2 + 0] * b2[e0 * DIM + d] + top_w[t * 2 + 1] * b2[e1 * DIM + d];
}

// ================================================================ Mode A GEMM1
// A = xh (f16, token-gathered rows), B = W1t (f16). All staging via
// global_load_lds width=16 -- no VGPR round trip, no in-loop cvt.
__global__ __launch_bounds__(256) void k_gemm1_a(
    const half_t* __restrict__ xh, const half_t* __restrict__ W1t,
    const float* __restrict__ b1, const int* __restrict__ pair_tok,
    const int* __restrict__ pad_off, const int* __restrict__ ptotal,
    half_t* __restrict__ hout, int j0, int Hc) {
  __shared__ half_t lds[16384];
  int P = *ptotal;
  int p0 = blockIdx.y * 128;
  if (p0 >= P) return;
  int e = 0;
#pragma unroll
  for (int q = 1; q < NE; ++q) if (p0 >= pad_off[q]) e = q;

  int tid = threadIdx.x, w = tid >> 6, l = tid & 63;
  int lr = l & 15, lq = l >> 4;
  int wr = w >> 1, wc = w & 1;
  int jt = blockIdx.x * 128;

  int tok0 = pair_tok[p0 + (2 * w) * 16 + lr];
  int tok1 = pair_tok[p0 + (2 * w + 1) * 16 + lr];
  const half_t* gA0 = xh + (size_t)tok0 * DIM + lq * 8;
  const half_t* gA1 = xh + (size_t)tok1 * DIM + lq * 8;
  const half_t* gB0 = W1t + ((size_t)e * Hc + jt + (2 * w) * 16 + lr) * DIM + lq * 8;
  const half_t* gB1 = W1t + ((size_t)e * Hc + jt + (2 * w + 1) * 16 + lr) * DIM + lq * 8;

  half_t* ldsA = lds;
  half_t* ldsB = lds + 8192;
  // wave-uniform LDS bases; lane l lands at base + l*16B (matches old layout)
  half_t* dA = ldsA + (4 * w) * 512;
  half_t* dB = ldsB + (4 * w) * 512;

  floatx4 acc[4][4];
#pragma unroll
  for (int i = 0; i < 4; ++i)
#pragma unroll
    for (int j = 0; j < 4; ++j) acc[i][j] = (floatx4){0.f, 0.f, 0.f, 0.f};

  for (int kt = 0; kt < DIM; kt += 64) {
    __syncthreads();                       // previous iteration's reads done
    gload16(gA0 + kt,      dA + 0 * 512);
    gload16(gA0 + kt + 32, dA + 1 * 512);
    gload16(gA1 + kt,      dA + 2 * 512);
    gload16(gA1 + kt + 32, dA + 3 * 512);
    gload16(gB0 + kt,      dB + 0 * 512);
    gload16(gB0 + kt + 32, dB + 1 * 512);
    gload16(gB1 + kt,      dB + 2 * 512);
    gload16(gB1 + kt + 32, dB + 3 * 512);
    __syncthreads();                       // vmcnt(0) drain -> tiles landed
#pragma unroll
    for (int ks = 0; ks < 2; ++ks) {
      half8 a[4], b[4];
#pragma unroll
      for (int i = 0; i < 4; ++i)
        a[i] = *(const half8*)(ldsA + ((4 * wr + i) * 2 + ks) * 512 + l * 8);
#pragma unroll
      for (int j = 0; j < 4; ++j)
        b[j] = *(const half8*)(ldsB + ((4 * wc + j) * 2 + ks) * 512 + l * 8);
#pragma unroll
      for (int i = 0; i < 4; ++i)
#pragma unroll
        for (int j = 0; j < 4; ++j)
          acc[i][j] = __builtin_amdgcn_mfma_f32_16x16x32_f16(a[i], b[j], acc[i][j], 0, 0, 0);
    }
  }
  __syncthreads();

#pragma unroll
  for (int j = 0; j < 4; ++j) {
    int coll = (4 * wc + j) * 16 + lr;
    float bias = b1[(size_t)e * HID + j0 + jt + coll];
#pragma unroll
    for (int i = 0; i < 4; ++i)
#pragma unroll
      for (int r = 0; r < 4; ++r) {
        int row = (4 * wr + i) * 16 + lq * 4 + r;
        lds[row * 128 + coll] = (half_t)silu_f(acc[i][j][r] + bias);
      }
  }
  __syncthreads();
#pragma unroll
  for (int ps = 0; ps < 4; ++ps) {
    int r = ps * 32 + (tid >> 3), c = (tid & 7) * 16;
    half8 v0 = *(const half8*)(lds + r * 128 + c);
    half8 v1 = *(const half8*)(lds + r * 128 + c + 8);
    half_t* dst = hout + (size_t)(p0 + r) * Hc + jt + c;
    *(half8*)dst = v0;
    *(half8*)(dst + 8) = v1;
  }
}

// ================================================================ Mode A GEMM2
__global__ __launch_bounds__(256) void k_gemm2_a(
    const half_t* __restrict__ hbuf, const half_t* __restrict__ W2t,
    const int* __restrict__ pair_tok, const float* __restrict__ pair_wt,
    const int* __restrict__ pad_off, const int* __restrict__ ptotal,
    float* __restrict__ out, int Hc) {
  __shared__ half_t lds[16384];
  int P = *ptotal;
  int p0 = blockIdx.y * 128;
  if (p0 >= P) return;
  int e = 0;
#pragma unroll
  for (int q = 1; q < NE; ++q) if (p0 >= pad_off[q]) e = q;

  int tid = threadIdx.x, w = tid >> 6, l = tid & 63;
  int lr = l & 15, lq = l >> 4;
  int wr = w >> 1, wc = w & 1;
  int jt = blockIdx.x * 128;

  const half_t* gA0 = hbuf + (size_t)(p0 + (2 * w) * 16 + lr) * Hc + lq * 8;
  const half_t* gA1 = hbuf + (size_t)(p0 + (2 * w + 1) * 16 + lr) * Hc + lq * 8;
  const half_t* gB0 = W2t + ((size_t)e * DIM + jt + (2 * w) * 16 + lr) * Hc + lq * 8;
  const half_t* gB1 = W2t + ((size_t)e * DIM + jt + (2 * w + 1) * 16 + lr) * Hc + lq * 8;

  half_t* ldsA = lds;
  half_t* ldsB = lds + 8192;
  half_t* dA = ldsA + (4 * w) * 512;
  half_t* dB = ldsB + (4 * w) * 512;

  floatx4 acc[4][4];
#pragma unroll
  for (int i = 0; i < 4; ++i)
#pragma unroll
    for (int j = 0; j < 4; ++j) acc[i][j] = (floatx4){0.f, 0.f, 0.f, 0.f};

  for (int kt = 0; kt < Hc; kt += 64) {
    __syncthreads();
    gload16(gA0 + kt,      dA + 0 * 512);
    gload16(gA0 + kt + 32, dA + 1 * 512);
    gload16(gA1 + kt,      dA + 2 * 512);
    gload16(gA1 + kt + 32, dA + 3 * 512);
    gload16(gB0 + kt,      dB + 0 * 512);
    gload16(gB0 + kt + 32, dB + 1 * 512);
    gload16(gB1 + kt,      dB + 2 * 512);
    gload16(gB1 + kt + 32, dB + 3 * 512);
    __syncthreads();
#pragma unroll
    for (int ks = 0; ks < 2; ++ks) {
      half8 a[4], b[4];
#pragma unroll
      for (int i = 0; i < 4; ++i)
        a[i] = *(const half8*)(ldsA + ((4 * wr + i) * 2 + ks) * 512 + l * 8);
#pragma unroll
      for (int j = 0; j < 4; ++j)
        b[j] = *(const half8*)(ldsB + ((4 * wc + j) * 2 + ks) * 512 + l * 8);
#pragma unroll
      for (int i = 0; i < 4; ++i)
#pragma unroll
        for (int j = 0; j < 4; ++j)
          acc[i][j] = __builtin_amdgcn_mfma_f32_16x16x32_f16(a[i], b[j], acc[i][j], 0, 0, 0);
    }
  }

#pragma unroll
  for (int i = 0; i < 4; ++i)
#pragma unroll
    for (int r = 0; r < 4; ++r) {
      int row = (4 * wr + i) * 16 + lq * 4 + r;
      float wt = pair_wt[p0 + row];
      if (wt != 0.0f) {
        int tok = pair_tok[p0 + row];
        float* op = out + (size_t)tok * DIM + jt;
#pragma unroll
        for (int j = 0; j < 4; ++j) {
          int coll = (4 * wc + j) * 16 + lr;
          unsafeAtomicAdd(op + coll, wt * acc[i][j][r]);
        }
      }
    }
}

// ================================================================ Mode B GEMM1 (fp32 W1 direct, A from xh)
__global__ __launch_bounds__(256) void k_gemm1_b(
    const half_t* __restrict__ xh, const float* __restrict__ W1,
    const float* __restrict__ b1, const int* __restrict__ pair_tok,
    const int* __restrict__ pad_off, const int* __restrict__ ptotal,
    half_t* __restrict__ hout, int j0, int Hc) {
  __shared__ half_t lds[16384];
  int P = *ptotal;
  int p0 = blockIdx.y * 128;
  if (p0 >= P) return;
  int e = 0;
#pragma unroll
  for (int q = 1; q < NE; ++q) if (p0 >= pad_off[q]) e = q;

  int tid = threadIdx.x, w = tid >> 6, l = tid & 63;
  int lr = l & 15, lq = l >> 4;
  int wr = w >> 1, wc = w & 1;
  int jt = blockIdx.x * 128;

  int tok0 = pair_tok[p0 + (2 * w) * 16 + lr];
  int tok1 = pair_tok[p0 + (2 * w + 1) * 16 + lr];
  const half_t* gA0 = xh + (size_t)tok0 * DIM + lq * 8;
  const half_t* gA1 = xh + (size_t)tok1 * DIM + lq * 8;
  const float* gBb = W1 + (size_t)e * DIM * HID + j0 + jt;
  const float* gB0 = gBb + (2 * w) * 16 + lr;
  const float* gB1 = gBb + (2 * w + 1) * 16 + lr;

  half_t* ldsA = lds;
  half_t* ldsB = lds + 8192;

  floatx4 acc[4][4];
#pragma unroll
  for (int i = 0; i < 4; ++i)
#pragma unroll
    for (int j = 0; j < 4; ++j) acc[i][j] = (floatx4){0.f, 0.f, 0.f, 0.f};

  for (int kt = 0; kt < DIM; kt += 64) {
    half8 va0 = *(const half8*)(gA0 + kt);
    half8 va1 = *(const half8*)(gA0 + kt + 32);
    half8 va2 = *(const half8*)(gA1 + kt);
    half8 va3 = *(const half8*)(gA1 + kt + 32);
    half8 vb[4];
#pragma unroll
    for (int fg = 0; fg < 4; ++fg) {
      const float* gb = (fg >> 1) ? gB1 : gB0;
      int kbase = kt + (fg & 1) * 32 + lq * 8;
#pragma unroll
      for (int j = 0; j < 8; ++j)
        vb[fg][j] = (half_t)gb[(size_t)(kbase + j) * HID];
    }
    __syncthreads();
    *(half8*)(ldsA + (4 * w + 0) * 512 + l * 8) = va0;
    *(half8*)(ldsA + (4 * w + 1) * 512 + l * 8) = va1;
    *(half8*)(ldsA + (4 * w + 2) * 512 + l * 8) = va2;
    *(half8*)(ldsA + (4 * w + 3) * 512 + l * 8) = va3;
    *(half8*)(ldsB + (4 * w + 0) * 512 + l * 8) = vb[0];
    *(half8*)(ldsB + (4 * w + 1) * 512 + l * 8) = vb[1];
    *(half8*)(ldsB + (4 * w + 2) * 512 + l * 8) = vb[2];
    *(half8*)(ldsB + (4 * w + 3) * 512 + l * 8) = vb[3];
    __syncthreads();
#pragma unroll
    for (int ks = 0; ks < 2; ++ks) {
      half8 a[4], b[4];
#pragma unroll
      for (int i = 0; i < 4; ++i)
        a[i] = *(const half8*)(ldsA + ((4 * wr + i) * 2 + ks) * 512 + l * 8);
#pragma unroll
      for (int j = 0; j < 4; ++j)
        b[j] = *(const half8*)(ldsB + ((4 * wc + j) * 2 + ks) * 512 + l * 8);
#pragma unroll
      for (int i = 0; i < 4; ++i)
#pragma unroll
        for (int j = 0; j < 4; ++j)
          acc[i][j] = __builtin_amdgcn_mfma_f32_16x16x32_f16(a[i], b[j], acc[i][j], 0, 0, 0);
    }
  }
  __syncthreads();

#pragma unroll
  for (int j = 0; j < 4; ++j) {
    int coll = (4 * wc + j) * 16 + lr;
    float bias = b1[(size_t)e * HID + j0 + jt + coll];
#pragma unroll
    for (int i = 0; i < 4; ++i)
#pragma unroll
      for (int r = 0; r < 4; ++r) {
        int row = (4 * wr + i) * 16 + lq * 4 + r;
        lds[row * 128 + coll] = (half_t)silu_f(acc[i][j][r] + bias);
      }
  }
  __syncthreads();
#pragma unroll
  for (int ps = 0; ps < 4; ++ps) {
    int r = ps * 32 + (tid >> 3), c = (tid & 7) * 16;
    half8 v0 = *(const half8*)(lds + r * 128 + c);
    half8 v1 = *(const half8*)(lds + r * 128 + c + 8);
    half_t* dst = hout + (size_t)(p0 + r) * Hc + jt + c;
    *(half8*)dst = v0;
    *(half8*)(dst + 8) = v1;
  }
}

// ================================================================ Mode B GEMM2 (fp32 W2 direct)
__global__ __launch_bounds__(256) void k_gemm2_b(
    const half_t* __restrict__ hbuf, const float* __restrict__ W2,
    const int* __restrict__ pair_tok, const float* __restrict__ pair_wt,
    const int* __restrict__ pad_off, const int* __restrict__ ptotal,
    float* __restrict__ out, int j0, int Hc) {
  __shared__ half_t lds[16384];
  int P = *ptotal;
  int p0 = blockIdx.y * 128;
  if (p0 >= P) return;
  int e = 0;
#pragma unroll
  for (int q = 1; q < NE; ++q) if (p0 >= pad_off[q]) e = q;

  int tid = threadIdx.x, w = tid >> 6, l = tid & 63;
  int lr = l & 15, lq = l >> 4;
  int wr = w >> 1, wc = w & 1;
  int jt = blockIdx.x * 128;

  const half_t* gA0 = hbuf + (size_t)(p0 + (2 * w) * 16 + lr) * Hc + lq * 8;
  const half_t* gA1 = hbuf + (size_t)(p0 + (2 * w + 1) * 16 + lr) * Hc + lq * 8;
  const float* gBb = W2 + (size_t)e * HID * DIM + jt;
  const float* gB0 = gBb + (2 * w) * 16 + lr;
  const float* gB1 = gBb + (2 * w + 1) * 16 + lr;

  half_t* ldsA = lds;
  half_t* ldsB = lds + 8192;

  floatx4 acc[4][4];
#pragma unroll
  for (int i = 0; i < 4; ++i)
#pragma unroll
    for (int j = 0; j < 4; ++j) acc[i][j] = (floatx4){0.f, 0.f, 0.f, 0.f};

  for (int kt = 0; kt < Hc; kt += 64) {
    half8 va0 = *(const half8*)(gA0 + kt);
    half8 va1 = *(const half8*)(gA0 + kt + 32);
    half8 va2 = *(const half8*)(gA1 + kt);
    half8 va3 = *(const half8*)(gA1 + kt + 32);
    half8 vb[4];
#pragma unroll
    for (int fg = 0; fg < 4; ++fg) {
      const float* gb = (fg >> 1) ? gB1 : gB0;
      int kbase = j0 + kt + (fg & 1) * 32 + lq * 8;
#pragma unroll
      for (int j = 0; j < 8; ++j)
        vb[fg][j] = (half_t)gb[(size_t)(kbase + j) * DIM];
    }
    __syncthreads();
    *(half8*)(ldsA + (4 * w + 0) * 512 + l * 8) = va0;
    *(half8*)(ldsA + (4 * w + 1) * 512 + l * 8) = va1;
    *(half8*)(ldsA + (4 * w + 2) * 512 + l * 8) = va2;
    *(half8*)(ldsA + (4 * w + 3) * 512 + l * 8) = va3;
    *(half8*)(ldsB + (4 * w + 0) * 512 + l * 8) = vb[0];
    *(half8*)(ldsB + (4 * w + 1) * 512 + l * 8) = vb[1];
    *(half8*)(ldsB + (4 * w + 2) * 512 + l * 8) = vb[2];
    *(half8*)(ldsB + (4 * w + 3) * 512 + l * 8) = vb[3];
    __syncthreads();
#pragma unroll
    for (int ks = 0; ks < 2; ++ks) {
      half8 a[4], b[4];
#pragma unroll
      for (int i = 0; i < 4; ++i)
        a[i] = *(const half8*)(ldsA + ((4 * wr + i) * 2 + ks) * 512 + l * 8);
#pragma unroll
      for (int j = 0; j < 4; ++j)
        b[j] = *(const half8*)(ldsB + ((4 * wc + j) * 2 + ks) * 512 + l * 8);
#pragma unroll
      for (int i = 0; i < 4; ++i)
#pragma unroll
        for (int j = 0; j < 4; ++j)
          acc[i][j] = __builtin_amdgcn_mfma_f32_16x16x32_f16(a[i], b[j], acc[i][j], 0, 0, 0);
    }
  }

#pragma unroll
  for (int i = 0; i < 4; ++i)
#pragma unroll
    for (int r = 0; r < 4; ++r) {
      int row = (4 * wr + i) * 16 + lq * 4 + r;
      float wt = pair_wt[p0 + row];
      if (wt != 0.0f) {
        int tok = pair_tok[p0 + row];
        float* op = out + (size_t)tok * DIM + jt;
#pragma unroll
        for (int j = 0; j < 4; ++j) {
          int coll = (4 * wc + j) * 16 + lr;
          unsafeAtomicAdd(op + coll, wt * acc[i][j][r]);
        }
      }
    }
}

// ---------------------------------------------------------------- launch
extern "C" void kernel_launch(void* const* d_in, const int* in_sizes, int n_in,
                              void* d_out, int out_size, void* d_ws, size_t ws_size,
                              hipStream_t stream) {
  const float* x  = (const float*)d_in[0];
  const float* Wg = (const float*)d_in[1];
  const float* W1 = (const float*)d_in[2];
  const float* b1 = (const float*)d_in[3];
  const float* W2 = (const float*)d_in[4];
  const float* b2 = (const float*)d_in[5];
  float* out = (float*)d_out;

  char* p = (char*)d_ws;
  auto alloc = [&](size_t bytes) -> char* {
    char* r = p; p += (bytes + 255) & ~(size_t)255; return r;
  };
  int*      top_i    = (int*)     alloc((size_t)T_TOK * 2 * sizeof(int));
  float*    top_w    = (float*)   alloc((size_t)T_TOK * 2 * sizeof(float));
  float*    prob_sum = (float*)   alloc(NE * sizeof(float));
  unsigned* cnt      = (unsigned*)alloc(NE * sizeof(unsigned));
  int*      pad_off  = (int*)     alloc((NE + 1) * sizeof(int));
  int*      ptotal   = (int*)     alloc(sizeof(int));
  unsigned* cursor   = (unsigned*)alloc(NE * sizeof(unsigned));
  int*      pair_tok = (int*)     alloc(PADMAX * sizeof(int));
  float*    pair_wt  = (float*)   alloc(PADMAX * sizeof(float));
  half_t*   xh       = (half_t*)  alloc((size_t)T_TOK * DIM * sizeof(half_t)); // 8 MB

  size_t used  = (size_t)(p - (char*)d_ws);
  size_t avail = ws_size > used ? ws_size - used : 0;

  // Mode A per-H-column cost: W1t + W2t (2*NE*DIM*2B) + hbuf (PADMAX*2B) = 51200 B
  size_t per_col_a = (size_t)2 * NE * DIM * sizeof(half_t) + (size_t)PADMAX * sizeof(half_t);
  int HcA = (int)((avail / per_col_a) & ~(size_t)127);
  if (HcA > HID) HcA = HID;
  bool modeA = (HcA >= 128);

  k_reset<<<dim3((PADMAX + 255) / 256), 256, 0, stream>>>(prob_sum, cnt, cursor, pair_tok, pair_wt);
  k_cvt_x<<<dim3((size_t)T_TOK * DIM / 8 / 256), 256, 0, stream>>>(x, xh);
  k_router<<<dim3(T_TOK / 16), 256, 0, stream>>>(x, Wg, top_i, top_w, prob_sum, cnt);
  k_scan<<<1, 64, 0, stream>>>(cnt, prob_sum, pad_off, ptotal, out + (size_t)T_TOK * DIM);
  k_scatter<<<dim3(T_TOK / 256), 256, 0, stream>>>(top_i, top_w, pad_off, cursor, pair_tok, pair_wt);
  k_init_out<<<dim3((size_t)T_TOK * DIM / 256), 256, 0, stream>>>(top_i, top_w, b2, out);

  if (modeA) {
    int Hc = HcA;
    half_t* W1t  = (half_t*)alloc((size_t)NE * Hc * DIM * sizeof(half_t));
    half_t* W2t  = (half_t*)alloc((size_t)NE * DIM * Hc * sizeof(half_t));
    half_t* hbuf = (half_t*)alloc((size_t)PADMAX * Hc * sizeof(half_t));
    for (int jb = 0; jb < HID; jb += Hc) {
      int hc = (HID - jb) < Hc ? (HID - jb) : Hc;   // multiple of 128
      k_tr_w1<<<dim3(hc / 64, DIM / 64, NE), 256, 0, stream>>>(W1, W1t, jb, hc);
      k_gemm1_a<<<dim3(hc / 128, PADMAX / 128), 256, 0, stream>>>(
          xh, W1t, b1, pair_tok, pad_off, ptotal, hbuf, jb, hc);
      k_tr_w2<<<dim3(DIM / 64, hc / 64, NE), 256, 0, stream>>>(W2, W2t, jb, hc);
      k_gemm2_a<<<dim3(DIM / 128, PADMAX / 128), 256, 0, stream>>>(
          hbuf, W2t, pair_tok, pair_wt, pad_off, ptotal, out, hc);
    }
  } else {
    // Mode B: only hbuf, fp32 weights read directly in the GEMMs.
    int Hc = (int)((avail / ((size_t)PADMAX * sizeof(half_t))) & ~(size_t)127);
    if (Hc > HID) Hc = HID;
    if (Hc < 128) Hc = 128;
    half_t* hbuf = (half_t*)alloc((size_t)PADMAX * Hc * sizeof(half_t));
    for (int jb = 0; jb < HID; jb += Hc) {
      int hc = (HID - jb) < Hc ? (HID - jb) : Hc;
      k_gemm1_b<<<dim3(hc / 128, PADMAX / 128), 256, 0, stream>>>(
          xh, W1, b1, pair_tok, pad_off, ptotal, hbuf, jb, hc);
      k_gemm2_b<<<dim3(DIM / 128, PADMAX / 128), 256, 0, stream>>>(
          hbuf, W2, pair_tok, pair_wt, pad_off, ptotal, out, jb, hc);
    }
  }
}

// Round 3
// 748.324 us; speedup vs baseline: 1.0456x; 1.0113x over previous
//
#include <hip/hip_runtime.h>
#include <cstdint>
#include <cstddef>

// Problem constants (B=2,S=2048 -> T=4096; D=1024; H=4096; E=8; top-k=2)
#define T_TOK 4096
#define DIM   1024
#define HID   4096
#define NE    8
#define PAD   128
#define PADMAX 9216   // sum_e ceil(cnt_e/128)*128 <= 8192 + 8*127 = 9208 -> 9216
#define KSPLIT2 4     // split-K factor for GEMM2 (epilogue is atomic -> free)

typedef _Float16 half_t;
typedef __attribute__((ext_vector_type(8))) _Float16 half8;
typedef __attribute__((ext_vector_type(4))) float floatx4;

__device__ __forceinline__ float silu_f(float v) {
  return v / (1.0f + expf(-v));
}

__device__ __forceinline__ half8 cvt44(float4 a, float4 b) {
  half8 o;
  o[0] = (half_t)a.x; o[1] = (half_t)a.y; o[2] = (half_t)a.z; o[3] = (half_t)a.w;
  o[4] = (half_t)b.x; o[5] = (half_t)b.y; o[6] = (half_t)b.z; o[7] = (half_t)b.w;
  return o;
}

// Async global->LDS, 16B per lane. LDS dest = wave-uniform base + lane*16B
// (m104/m108); global src addr is per-lane (gather OK). Data is guaranteed
// landed after __syncthreads() (compiler drains vmcnt(0) before s_barrier).
__device__ __forceinline__ void gload16(const void* g, void* l) {
  __builtin_amdgcn_global_load_lds(
      (const __attribute__((address_space(1))) unsigned int*)g,
      (__attribute__((address_space(3))) unsigned int*)l, 16, 0, 0);
}

// Bijective XCD swizzle (m204 simple form; requires Nw % 8 == 0, which both
// GEMM grids satisfy by construction: 72 = 8*9). Hardware round-robins linear
// block id over 8 XCDs; this gives XCD k the contiguous work chunk
// [k*Nw/8, (k+1)*Nw/8) so consecutive work items share L2-resident panels.
__device__ __forceinline__ int xcd_swz(int lin, int Nw) {
  int q = Nw >> 3;
  return (lin & 7) * q + (lin >> 3);
}

// ---------------------------------------------------------------- reset
__global__ void k_reset(float* prob_sum, unsigned* cnt, unsigned* cursor,
                        int* pair_tok, float* pair_wt) {
  int i = blockIdx.x * 256 + threadIdx.x;
  if (i < PADMAX) { pair_tok[i] = 0; pair_wt[i] = 0.0f; }
  if (i < NE) { prob_sum[i] = 0.0f; cnt[i] = 0u; cursor[i] = 0u; }
}

// ---------------------------------------------------------------- x fp32 -> f16 (once)
__global__ __launch_bounds__(256) void k_cvt_x(const float* __restrict__ x,
                                               half_t* __restrict__ xh) {
  size_t i = (size_t)blockIdx.x * 256 + threadIdx.x;   // one half8 per thread
  const float4* s = (const float4*)(x + i * 8);
  float4 a = s[0], b = s[1];
  *(half8*)(xh + i * 8) = cvt44(a, b);
}

// ---------------------------------------------------------------- W1 [E][D][H] -> W1t [E][Hc][D] f16
__global__ __launch_bounds__(256) void k_tr_w1(const float* __restrict__ W1,
                                               half_t* __restrict__ W1t,
                                               int j0, int Hc) {
  __shared__ half_t T[64][72];
  int e = blockIdx.z, h0 = blockIdx.x * 64, d0 = blockIdx.y * 64;
  int tid = threadIdx.x;
  {
    int r = tid >> 2, c16 = (tid & 3) * 16;
    const float* s = W1 + ((size_t)e * DIM + d0 + r) * HID + j0 + h0 + c16;
    float4 a = ((const float4*)s)[0], b = ((const float4*)s)[1];
    float4 c = ((const float4*)s)[2], d = ((const float4*)s)[3];
    *(half8*)&T[r][c16] = cvt44(a, b);
    *(half8*)&T[r][c16 + 8] = cvt44(c, d);
  }
  __syncthreads();
  {
    int n = tid >> 2, d16 = (tid & 3) * 16;
    half8 u, v;
#pragma unroll
    for (int j = 0; j < 8; ++j) { u[j] = T[d16 + j][n]; v[j] = T[d16 + 8 + j][n]; }
    half_t* dst = W1t + ((size_t)e * Hc + h0 + n) * DIM + d0 + d16;
    *(half8*)dst = u;
    *(half8*)(dst + 8) = v;
  }
}

// ---------------------------------------------------------------- W2 [E][H][D] -> W2t [E][D][Hc] f16
__global__ __launch_bounds__(256) void k_tr_w2(const float* __restrict__ W2,
                                               half_t* __restrict__ W2t,
                                               int j0, int Hc) {
  __shared__ half_t T[64][72];
  int e = blockIdx.z, d0 = blockIdx.x * 64, h0 = blockIdx.y * 64;
  int tid = threadIdx.x;
  {
    int r = tid >> 2, c16 = (tid & 3) * 16;
    const float* s = W2 + ((size_t)e * HID + j0 + h0 + r) * DIM + d0 + c16;
    float4 a = ((const float4*)s)[0], b = ((const float4*)s)[1];
    float4 c = ((const float4*)s)[2], d = ((const float4*)s)[3];
    *(half8*)&T[r][c16] = cvt44(a, b);
    *(half8*)&T[r][c16 + 8] = cvt44(c, d);
  }
  __syncthreads();
  {
    int n = tid >> 2, h16 = (tid & 3) * 16;
    half8 u, v;
#pragma unroll
    for (int j = 0; j < 8; ++j) { u[j] = T[h16 + j][n]; v[j] = T[h16 + 8 + j][n]; }
    half_t* dst = W2t + ((size_t)e * DIM + d0 + n) * Hc + h0 + h16;
    *(half8*)dst = u;
    *(half8*)(dst + 8) = v;
  }
}

// ---------------------------------------------------------------- router
__global__ __launch_bounds__(256) void k_router(
    const float* __restrict__ x, const float* __restrict__ Wg,
    int* __restrict__ top_i, float* __restrict__ top_w,
    float* __restrict__ prob_sum, unsigned* __restrict__ cnt) {
  __shared__ float sWg[NE * DIM];
  __shared__ float sProb[NE];
  __shared__ unsigned sCnt[NE];
  int tid = threadIdx.x;
  if (tid < NE) { sProb[tid] = 0.0f; sCnt[tid] = 0u; }
  for (int i = tid; i < NE * DIM; i += 256) sWg[i] = Wg[i];
  __syncthreads();

  int wave = tid >> 6, lane = tid & 63;
  for (int it = 0; it < 4; ++it) {
    int t = blockIdx.x * 16 + wave * 4 + it;
    const float* xp = x + (size_t)t * DIM;
    float acc[NE];
#pragma unroll
    for (int e = 0; e < NE; ++e) acc[e] = 0.0f;
    for (int i = 0; i < DIM / 64; ++i) {
      int d = i * 64 + lane;
      float xd = xp[d];
#pragma unroll
      for (int e = 0; e < NE; ++e) acc[e] = fmaf(xd, sWg[e * DIM + d], acc[e]);
    }
#pragma unroll
    for (int off = 32; off > 0; off >>= 1)
#pragma unroll
      for (int e = 0; e < NE; ++e) acc[e] += __shfl_xor(acc[e], off, 64);

    if (lane == 0) {
      float m = acc[0];
#pragma unroll
      for (int e = 1; e < NE; ++e) m = fmaxf(m, acc[e]);
      float pr[NE]; float s = 0.0f;
#pragma unroll
      for (int e = 0; e < NE; ++e) { pr[e] = expf(acc[e] - m); s += pr[e]; }
      float inv = 1.0f / s;
#pragma unroll
      for (int e = 0; e < NE; ++e) pr[e] *= inv;
      int i0 = 0; float v0 = pr[0];
#pragma unroll
      for (int e = 1; e < NE; ++e) if (pr[e] > v0) { v0 = pr[e]; i0 = e; }
      int i1 = -1; float v1 = -1.0f;
#pragma unroll
      for (int e = 0; e < NE; ++e) if (e != i0 && pr[e] > v1) { v1 = pr[e]; i1 = e; }
      float wn = 1.0f / (v0 + v1);
      top_i[t * 2 + 0] = i0; top_i[t * 2 + 1] = i1;
      top_w[t * 2 + 0] = v0 * wn; top_w[t * 2 + 1] = v1 * wn;
#pragma unroll
      for (int e = 0; e < NE; ++e) atomicAdd(&sProb[e], pr[e]);
      atomicAdd(&sCnt[i0], 1u);
      atomicAdd(&sCnt[i1], 1u);
    }
  }
  __syncthreads();
  if (tid < NE) {
    atomicAdd(&prob_sum[tid], sProb[tid]);
    atomicAdd(&cnt[tid], sCnt[tid]);
  }
}

// ---------------------------------------------------------------- scan + aux loss
__global__ void k_scan(const unsigned* __restrict__ cnt,
                       const float* __restrict__ prob_sum,
                       int* __restrict__ pad_off, int* __restrict__ ptotal,
                       float* __restrict__ aux_out) {
  if (threadIdx.x == 0 && blockIdx.x == 0) {
    int off = 0; float aux = 0.0f;
    for (int e = 0; e < NE; ++e) {
      pad_off[e] = off;
      off += (int)((cnt[e] + (PAD - 1u)) & ~(unsigned)(PAD - 1));
      aux += ((float)cnt[e] / (float)T_TOK) * (prob_sum[e] / (float)T_TOK);
    }
    pad_off[NE] = off;
    *ptotal = off;
    *aux_out = (float)NE * aux;
  }
}

// ---------------------------------------------------------------- scatter pairs
__global__ void k_scatter(const int* __restrict__ top_i, const float* __restrict__ top_w,
                          const int* __restrict__ pad_off, unsigned* __restrict__ cursor,
                          int* __restrict__ pair_tok, float* __restrict__ pair_wt) {
  int t = blockIdx.x * 256 + threadIdx.x;
  if (t >= T_TOK) return;
#pragma unroll
  for (int k = 0; k < 2; ++k) {
    int e = top_i[t * 2 + k];
    unsigned pos = atomicAdd(&cursor[e], 1u);
    int idx = pad_off[e] + (int)pos;
    pair_tok[idx] = t;
    pair_wt[idx]  = top_w[t * 2 + k];
  }
}

// ---------------------------------------------------------------- out = w0*b2[e0] + w1*b2[e1]
__global__ void k_init_out(const int* __restrict__ top_i, const float* __restrict__ top_w,
                           const float* __restrict__ b2, float* __restrict__ out) {
  int idx = blockIdx.x * 256 + threadIdx.x;
  int t = idx >> 10, d = idx & (DIM - 1);
  int e0 = top_i[t * 2 + 0], e1 = top_i[t * 2 + 1];
  out[idx] = top_w[t * 2 + 0] * b2[e0 * DIM + d] + top_w[t * 2 + 1] * b2[e1 * DIM + d];
}

// ================================================================ Mode A GEMM1
// 1D grid, XCD-swizzled. Work order: row fastest within a column group so
// each XCD reuses one W1t column panel (256 KB, L2-hot) across 72 row tiles.
__global__ __launch_bounds__(256) void k_gemm1_a(
    const half_t* __restrict__ xh, const half_t* __restrict__ W1t,
    const float* __restrict__ b1, const int* __restrict__ pair_tok,
    const int* __restrict__ pad_off, const int* __restrict__ ptotal,
    half_t* __restrict__ hout, int j0, int Hc) {
  __shared__ half_t lds[16384];
  int wid = xcd_swz(blockIdx.x, gridDim.x);
  int col = wid / (PADMAX / 128);          // H-column tile
  int row = wid % (PADMAX / 128);          // token-pair row tile
  int P = *ptotal;
  int p0 = row * 128;
  if (p0 >= P) return;
  int e = 0;
#pragma unroll
  for (int q = 1; q < NE; ++q) if (p0 >= pad_off[q]) e = q;

  int tid = threadIdx.x, w = tid >> 6, l = tid & 63;
  int lr = l & 15, lq = l >> 4;
  int wr = w >> 1, wc = w & 1;
  int jt = col * 128;

  int tok0 = pair_tok[p0 + (2 * w) * 16 + lr];
  int tok1 = pair_tok[p0 + (2 * w + 1) * 16 + lr];
  const half_t* gA0 = xh + (size_t)tok0 * DIM + lq * 8;
  const half_t* gA1 = xh + (size_t)tok1 * DIM + lq * 8;
  const half_t* gB0 = W1t + ((size_t)e * Hc + jt + (2 * w) * 16 + lr) * DIM + lq * 8;
  const half_t* gB1 = W1t + ((size_t)e * Hc + jt + (2 * w + 1) * 16 + lr) * DIM + lq * 8;

  half_t* ldsA = lds;
  half_t* ldsB = lds + 8192;
  half_t* dA = ldsA + (4 * w) * 512;
  half_t* dB = ldsB + (4 * w) * 512;

  floatx4 acc[4][4];
#pragma unroll
  for (int i = 0; i < 4; ++i)
#pragma unroll
    for (int j = 0; j < 4; ++j) acc[i][j] = (floatx4){0.f, 0.f, 0.f, 0.f};

  for (int kt = 0; kt < DIM; kt += 64) {
    __syncthreads();                       // previous iteration's reads done
    gload16(gA0 + kt,      dA + 0 * 512);
    gload16(gA0 + kt + 32, dA + 1 * 512);
    gload16(gA1 + kt,      dA + 2 * 512);
    gload16(gA1 + kt + 32, dA + 3 * 512);
    gload16(gB0 + kt,      dB + 0 * 512);
    gload16(gB0 + kt + 32, dB + 1 * 512);
    gload16(gB1 + kt,      dB + 2 * 512);
    gload16(gB1 + kt + 32, dB + 3 * 512);
    __syncthreads();                       // vmcnt(0) drain -> tiles landed
#pragma unroll
    for (int ks = 0; ks < 2; ++ks) {
      half8 a[4], b[4];
#pragma unroll
      for (int i = 0; i < 4; ++i)
        a[i] = *(const half8*)(ldsA + ((4 * wr + i) * 2 + ks) * 512 + l * 8);
#pragma unroll
      for (int j = 0; j < 4; ++j)
        b[j] = *(const half8*)(ldsB + ((4 * wc + j) * 2 + ks) * 512 + l * 8);
#pragma unroll
      for (int i = 0; i < 4; ++i)
#pragma unroll
        for (int j = 0; j < 4; ++j)
          acc[i][j] = __builtin_amdgcn_mfma_f32_16x16x32_f16(a[i], b[j], acc[i][j], 0, 0, 0);
    }
  }
  __syncthreads();

#pragma unroll
  for (int j = 0; j < 4; ++j) {
    int coll = (4 * wc + j) * 16 + lr;
    float bias = b1[(size_t)e * HID + j0 + jt + coll];
#pragma unroll
    for (int i = 0; i < 4; ++i)
#pragma unroll
      for (int r = 0; r < 4; ++r) {
        int row2 = (4 * wr + i) * 16 + lq * 4 + r;
        lds[row2 * 128 + coll] = (half_t)silu_f(acc[i][j][r] + bias);
      }
  }
  __syncthreads();
#pragma unroll
  for (int ps = 0; ps < 4; ++ps) {
    int r = ps * 32 + (tid >> 3), c = (tid & 7) * 16;
    half8 v0 = *(const half8*)(lds + r * 128 + c);
    half8 v1 = *(const half8*)(lds + r * 128 + c + 8);
    half_t* dst = hout + (size_t)(p0 + r) * Hc + jt + c;
    *(half8*)dst = v0;
    *(half8*)(dst + 8) = v1;
  }
}

// ================================================================ Mode A GEMM2
// 1D grid, XCD-swizzled, split-K by KSPLIT2. Work order: column fastest so
// one A row panel is consumed by all 8 D-column tiles within one XCD chunk
// (A fetched once); B chunks (8 x 256 KB = 2 MB) stay L2-resident.
__global__ __launch_bounds__(256) void k_gemm2_a(
    const half_t* __restrict__ hbuf, const half_t* __restrict__ W2t,
    const int* __restrict__ pair_tok, const float* __restrict__ pair_wt,
    const int* __restrict__ pad_off, const int* __restrict__ ptotal,
    float* __restrict__ out, int Hc) {
  __shared__ half_t lds[16384];
  int wid = xcd_swz(blockIdx.x, gridDim.x);
  int c  = wid & 7;                 // D-column tile (DIM/128 = 8)
  int rz = wid >> 3;
  int row = rz % (PADMAX / 128);    // token-pair row tile
  int zk  = rz / (PADMAX / 128);    // K-split index
  int P = *ptotal;
  int p0 = row * 128;
  if (p0 >= P) return;
  int e = 0;
#pragma unroll
  for (int q = 1; q < NE; ++q) if (p0 >= pad_off[q]) e = q;

  int tid = threadIdx.x, w = tid >> 6, l = tid & 63;
  int lr = l & 15, lq = l >> 4;
  int wr = w >> 1, wc = w & 1;
  int jt = c * 128;

  // K-range for this split (multiples of 64; handles any Hc multiple of 128)
  int ks_total = Hc >> 6;
  int kt_beg = ((zk * ks_total) / KSPLIT2) * 64;
  int kt_end = (((zk + 1) * ks_total) / KSPLIT2) * 64;

  const half_t* gA0 = hbuf + (size_t)(p0 + (2 * w) * 16 + lr) * Hc + lq * 8;
  const half_t* gA1 = hbuf + (size_t)(p0 + (2 * w + 1) * 16 + lr) * Hc + lq * 8;
  const half_t* gB0 = W2t + ((size_t)e * DIM + jt + (2 * w) * 16 + lr) * Hc + lq * 8;
  const half_t* gB1 = W2t + ((size_t)e * DIM + jt + (2 * w + 1) * 16 + lr) * Hc + lq * 8;

  half_t* ldsA = lds;
  half_t* ldsB = lds + 8192;
  half_t* dA = ldsA + (4 * w) * 512;
  half_t* dB = ldsB + (4 * w) * 512;

  floatx4 acc[4][4];
#pragma unroll
  for (int i = 0; i < 4; ++i)
#pragma unroll
    for (int j = 0; j < 4; ++j) acc[i][j] = (floatx4){0.f, 0.f, 0.f, 0.f};

  for (int kt = kt_beg; kt < kt_end; kt += 64) {
    __syncthreads();
    gload16(gA0 + kt,      dA + 0 * 512);
    gload16(gA0 + kt + 32, dA + 1 * 512);
    gload16(gA1 + kt,      dA + 2 * 512);
    gload16(gA1 + kt + 32, dA + 3 * 512);
    gload16(gB0 + kt,      dB + 0 * 512);
    gload16(gB0 + kt + 32, dB + 1 * 512);
    gload16(gB1 + kt,      dB + 2 * 512);
    gload16(gB1 + kt + 32, dB + 3 * 512);
    __syncthreads();
#pragma unroll
    for (int ks = 0; ks < 2; ++ks) {
      half8 a[4], b[4];
#pragma unroll
      for (int i = 0; i < 4; ++i)
        a[i] = *(const half8*)(ldsA + ((4 * wr + i) * 2 + ks) * 512 + l * 8);
#pragma unroll
      for (int j = 0; j < 4; ++j)
        b[j] = *(const half8*)(ldsB + ((4 * wc + j) * 2 + ks) * 512 + l * 8);
#pragma unroll
      for (int i = 0; i < 4; ++i)
#pragma unroll
        for (int j = 0; j < 4; ++j)
          acc[i][j] = __builtin_amdgcn_mfma_f32_16x16x32_f16(a[i], b[j], acc[i][j], 0, 0, 0);
    }
  }

#pragma unroll
  for (int i = 0; i < 4; ++i)
#pragma unroll
    for (int r = 0; r < 4; ++r) {
      int row2 = (4 * wr + i) * 16 + lq * 4 + r;
      float wt = pair_wt[p0 + row2];
      if (wt != 0.0f) {
        int tok = pair_tok[p0 + row2];
        float* op = out + (size_t)tok * DIM + jt;
#pragma unroll
        for (int j = 0; j < 4; ++j) {
          int coll = (4 * wc + j) * 16 + lr;
          unsafeAtomicAdd(op + coll, wt * acc[i][j][r]);
        }
      }
    }
}

// ================================================================ Mode B GEMM1 (fp32 W1 direct, A from xh)
__global__ __launch_bounds__(256) void k_gemm1_b(
    const half_t* __restrict__ xh, const float* __restrict__ W1,
    const float* __restrict__ b1, const int* __restrict__ pair_tok,
    const int* __restrict__ pad_off, const int* __restrict__ ptotal,
    half_t* __restrict__ hout, int j0, int Hc) {
  __shared__ half_t lds[16384];
  int P = *ptotal;
  int p0 = blockIdx.y * 128;
  if (p0 >= P) return;
  int e = 0;
#pragma unroll
  for (int q = 1; q < NE; ++q) if (p0 >= pad_off[q]) e = q;

  int tid = threadIdx.x, w = tid >> 6, l = tid & 63;
  int lr = l & 15, lq = l >> 4;
  int wr = w >> 1, wc = w & 1;
  int jt = blockIdx.x * 128;

  int tok0 = pair_tok[p0 + (2 * w) * 16 + lr];
  int tok1 = pair_tok[p0 + (2 * w + 1) * 16 + lr];
  const half_t* gA0 = xh + (size_t)tok0 * DIM + lq * 8;
  const half_t* gA1 = xh + (size_t)tok1 * DIM + lq * 8;
  const float* gBb = W1 + (size_t)e * DIM * HID + j0 + jt;
  const float* gB0 = gBb + (2 * w) * 16 + lr;
  const float* gB1 = gBb + (2 * w + 1) * 16 + lr;

  half_t* ldsA = lds;
  half_t* ldsB = lds + 8192;

  floatx4 acc[4][4];
#pragma unroll
  for (int i = 0; i < 4; ++i)
#pragma unroll
    for (int j = 0; j < 4; ++j) acc[i][j] = (floatx4){0.f, 0.f, 0.f, 0.f};

  for (int kt = 0; kt < DIM; kt += 64) {
    half8 va0 = *(const half8*)(gA0 + kt);
    half8 va1 = *(const half8*)(gA0 + kt + 32);
    half8 va2 = *(const half8*)(gA1 + kt);
    half8 va3 = *(const half8*)(gA1 + kt + 32);
    half8 vb[4];
#pragma unroll
    for (int fg = 0; fg < 4; ++fg) {
      const float* gb = (fg >> 1) ? gB1 : gB0;
      int kbase = kt + (fg & 1) * 32 + lq * 8;
#pragma unroll
      for (int j = 0; j < 8; ++j)
        vb[fg][j] = (half_t)gb[(size_t)(kbase + j) * HID];
    }
    __syncthreads();
    *(half8*)(ldsA + (4 * w + 0) * 512 + l * 8) = va0;
    *(half8*)(ldsA + (4 * w + 1) * 512 + l * 8) = va1;
    *(half8*)(ldsA + (4 * w + 2) * 512 + l * 8) = va2;
    *(half8*)(ldsA + (4 * w + 3) * 512 + l * 8) = va3;
    *(half8*)(ldsB + (4 * w + 0) * 512 + l * 8) = vb[0];
    *(half8*)(ldsB + (4 * w + 1) * 512 + l * 8) = vb[1];
    *(half8*)(ldsB + (4 * w + 2) * 512 + l * 8) = vb[2];
    *(half8*)(ldsB + (4 * w + 3) * 512 + l * 8) = vb[3];
    __syncthreads();
#pragma unroll
    for (int ks = 0; ks < 2; ++ks) {
      half8 a[4], b[4];
#pragma unroll
      for (int i = 0; i < 4; ++i)
        a[i] = *(const half8*)(ldsA + ((4 * wr + i) * 2 + ks) * 512 + l * 8);
#pragma unroll
      for (int j = 0; j < 4; ++j)
        b[j] = *(const half8*)(ldsB + ((4 * wc + j) * 2 + ks) * 512 + l * 8);
#pragma unroll
      for (int i = 0; i < 4; ++i)
#pragma unroll
        for (int j = 0; j < 4; ++j)
          acc[i][j] = __builtin_amdgcn_mfma_f32_16x16x32_f16(a[i], b[j], acc[i][j], 0, 0, 0);
    }
  }
  __syncthreads();

#pragma unroll
  for (int j = 0; j < 4; ++j) {
    int coll = (4 * wc + j) * 16 + lr;
    float bias = b1[(size_t)e * HID + j0 + jt + coll];
#pragma unroll
    for (int i = 0; i < 4; ++i)
#pragma unroll
      for (int r = 0; r < 4; ++r) {
        int row = (4 * wr + i) * 16 + lq * 4 + r;
        lds[row * 128 + coll] = (half_t)silu_f(acc[i][j][r] + bias);
      }
  }
  __syncthreads();
#pragma unroll
  for (int ps = 0; ps < 4; ++ps) {
    int r = ps * 32 + (tid >> 3), c = (tid & 7) * 16;
    half8 v0 = *(const half8*)(lds + r * 128 + c);
    half8 v1 = *(const half8*)(lds + r * 128 + c + 8);
    half_t* dst = hout + (size_t)(p0 + r) * Hc + jt + c;
    *(half8*)dst = v0;
    *(half8*)(dst + 8) = v1;
  }
}

// ================================================================ Mode B GEMM2 (fp32 W2 direct)
__global__ __launch_bounds__(256) void k_gemm2_b(
    const half_t* __restrict__ hbuf, const float* __restrict__ W2,
    const int* __restrict__ pair_tok, const float* __restrict__ pair_wt,
    const int* __restrict__ pad_off, const int* __restrict__ ptotal,
    float* __restrict__ out, int j0, int Hc) {
  __shared__ half_t lds[16384];
  int P = *ptotal;
  int p0 = blockIdx.y * 128;
  if (p0 >= P) return;
  int e = 0;
#pragma unroll
  for (int q = 1; q < NE; ++q) if (p0 >= pad_off[q]) e = q;

  int tid = threadIdx.x, w = tid >> 6, l = tid & 63;
  int lr = l & 15, lq = l >> 4;
  int wr = w >> 1, wc = w & 1;
  int jt = blockIdx.x * 128;

  const half_t* gA0 = hbuf + (size_t)(p0 + (2 * w) * 16 + lr) * Hc + lq * 8;
  const half_t* gA1 = hbuf + (size_t)(p0 + (2 * w + 1) * 16 + lr) * Hc + lq * 8;
  const float* gBb = W2 + (size_t)e * HID * DIM + jt;
  const float* gB0 = gBb + (2 * w) * 16 + lr;
  const float* gB1 = gBb + (2 * w + 1) * 16 + lr;

  half_t* ldsA = lds;
  half_t* ldsB = lds + 8192;

  floatx4 acc[4][4];
#pragma unroll
  for (int i = 0; i < 4; ++i)
#pragma unroll
    for (int j = 0; j < 4; ++j) acc[i][j] = (floatx4){0.f, 0.f, 0.f, 0.f};

  for (int kt = 0; kt < Hc; kt += 64) {
    half8 va0 = *(const half8*)(gA0 + kt);
    half8 va1 = *(const half8*)(gA0 + kt + 32);
    half8 va2 = *(const half8*)(gA1 + kt);
    half8 va3 = *(const half8*)(gA1 + kt + 32);
    half8 vb[4];
#pragma unroll
    for (int fg = 0; fg < 4; ++fg) {
      const float* gb = (fg >> 1) ? gB1 : gB0;
      int kbase = j0 + kt + (fg & 1) * 32 + lq * 8;
#pragma unroll
      for (int j = 0; j < 8; ++j)
        vb[fg][j] = (half_t)gb[(size_t)(kbase + j) * DIM];
    }
    __syncthreads();
    *(half8*)(ldsA + (4 * w + 0) * 512 + l * 8) = va0;
    *(half8*)(ldsA + (4 * w + 1) * 512 + l * 8) = va1;
    *(half8*)(ldsA + (4 * w + 2) * 512 + l * 8) = va2;
    *(half8*)(ldsA + (4 * w + 3) * 512 + l * 8) = va3;
    *(half8*)(ldsB + (4 * w + 0) * 512 + l * 8) = vb[0];
    *(half8*)(ldsB + (4 * w + 1) * 512 + l * 8) = vb[1];
    *(half8*)(ldsB + (4 * w + 2) * 512 + l * 8) = vb[2];
    *(half8*)(ldsB + (4 * w + 3) * 512 + l * 8) = vb[3];
    __syncthreads();
#pragma unroll
    for (int ks = 0; ks < 2; ++ks) {
      half8 a[4], b[4];
#pragma unroll
      for (int i = 0; i < 4; ++i)
        a[i] = *(const half8*)(ldsA + ((4 * wr + i) * 2 + ks) * 512 + l * 8);
#pragma unroll
      for (int j = 0; j < 4; ++j)
        b[j] = *(const half8*)(ldsB + ((4 * wc + j) * 2 + ks) * 512 + l * 8);
#pragma unroll
      for (int i = 0; i < 4; ++i)
#pragma unroll
        for (int j = 0; j < 4; ++j)
          acc[i][j] = __builtin_amdgcn_mfma_f32_16x16x32_f16(a[i], b[j], acc[i][j], 0, 0, 0);
    }
  }

#pragma unroll
  for (int i = 0; i < 4; ++i)
#pragma unroll
    for (int r = 0; r < 4; ++r) {
      int row = (4 * wr + i) * 16 + lq * 4 + r;
      float wt = pair_wt[p0 + row];
      if (wt != 0.0f) {
        int tok = pair_tok[p0 + row];
        float* op = out + (size_t)tok * DIM + jt;
#pragma unroll
        for (int j = 0; j < 4; ++j) {
          int coll = (4 * wc + j) * 16 + lr;
          unsafeAtomicAdd(op + coll, wt * acc[i][j][r]);
        }
      }
    }
}

// ---------------------------------------------------------------- launch
extern "C" void kernel_launch(void* const* d_in, const int* in_sizes, int n_in,
                              void* d_out, int out_size, void* d_ws, size_t ws_size,
                              hipStream_t stream) {
  const float* x  = (const float*)d_in[0];
  const float* Wg = (const float*)d_in[1];
  const float* W1 = (const float*)d_in[2];
  const float* b1 = (const float*)d_in[3];
  const float* W2 = (const float*)d_in[4];
  const float* b2 = (const float*)d_in[5];
  float* out = (float*)d_out;

  char* p = (char*)d_ws;
  auto alloc = [&](size_t bytes) -> char* {
    char* r = p; p += (bytes + 255) & ~(size_t)255; return r;
  };
  int*      top_i    = (int*)     alloc((size_t)T_TOK * 2 * sizeof(int));
  float*    top_w    = (float*)   alloc((size_t)T_TOK * 2 * sizeof(float));
  float*    prob_sum = (float*)   alloc(NE * sizeof(float));
  unsigned* cnt      = (unsigned*)alloc(NE * sizeof(unsigned));
  int*      pad_off  = (int*)     alloc((NE + 1) * sizeof(int));
  int*      ptotal   = (int*)     alloc(sizeof(int));
  unsigned* cursor   = (unsigned*)alloc(NE * sizeof(unsigned));
  int*      pair_tok = (int*)     alloc(PADMAX * sizeof(int));
  float*    pair_wt  = (float*)   alloc(PADMAX * sizeof(float));
  half_t*   xh       = (half_t*)  alloc((size_t)T_TOK * DIM * sizeof(half_t)); // 8 MB

  size_t used  = (size_t)(p - (char*)d_ws);
  size_t avail = ws_size > used ? ws_size - used : 0;

  // Mode A per-H-column cost: W1t + W2t (2*NE*DIM*2B) + hbuf (PADMAX*2B) = 51200 B
  size_t per_col_a = (size_t)2 * NE * DIM * sizeof(half_t) + (size_t)PADMAX * sizeof(half_t);
  int HcA = (int)((avail / per_col_a) & ~(size_t)127);
  if (HcA > HID) HcA = HID;
  bool modeA = (HcA >= 128);

  k_reset<<<dim3((PADMAX + 255) / 256), 256, 0, stream>>>(prob_sum, cnt, cursor, pair_tok, pair_wt);
  k_cvt_x<<<dim3((size_t)T_TOK * DIM / 8 / 256), 256, 0, stream>>>(x, xh);
  k_router<<<dim3(T_TOK / 16), 256, 0, stream>>>(x, Wg, top_i, top_w, prob_sum, cnt);
  k_scan<<<1, 64, 0, stream>>>(cnt, prob_sum, pad_off, ptotal, out + (size_t)T_TOK * DIM);
  k_scatter<<<dim3(T_TOK / 256), 256, 0, stream>>>(top_i, top_w, pad_off, cursor, pair_tok, pair_wt);
  k_init_out<<<dim3((size_t)T_TOK * DIM / 256), 256, 0, stream>>>(top_i, top_w, b2, out);

  if (modeA) {
    int Hc = HcA;
    half_t* W1t  = (half_t*)alloc((size_t)NE * Hc * DIM * sizeof(half_t));
    half_t* W2t  = (half_t*)alloc((size_t)NE * DIM * Hc * sizeof(half_t));
    half_t* hbuf = (half_t*)alloc((size_t)PADMAX * Hc * sizeof(half_t));
    for (int jb = 0; jb < HID; jb += Hc) {
      int hc = (HID - jb) < Hc ? (HID - jb) : Hc;   // multiple of 128
      k_tr_w1<<<dim3(hc / 64, DIM / 64, NE), 256, 0, stream>>>(W1, W1t, jb, hc);
      // 1D swizzled grid: (hc/128) cols x 72 rows; 72 = 8*9 keeps Nw % 8 == 0
      k_gemm1_a<<<dim3((hc / 128) * (PADMAX / 128)), 256, 0, stream>>>(
          xh, W1t, b1, pair_tok, pad_off, ptotal, hbuf, jb, hc);
      k_tr_w2<<<dim3(DIM / 64, hc / 64, NE), 256, 0, stream>>>(W2, W2t, jb, hc);
      // 1D swizzled grid: 8 cols x 72 rows x KSPLIT2 = 2304 blocks
      k_gemm2_a<<<dim3((DIM / 128) * (PADMAX / 128) * KSPLIT2), 256, 0, stream>>>(
          hbuf, W2t, pair_tok, pair_wt, pad_off, ptotal, out, hc);
    }
  } else {
    // Mode B: only hbuf, fp32 weights read directly in the GEMMs.
    int Hc = (int)((avail / ((size_t)PADMAX * sizeof(half_t))) & ~(size_t)127);
    if (Hc > HID) Hc = HID;
    if (Hc < 128) Hc = 128;
    half_t* hbuf = (half_t*)alloc((size_t)PADMAX * Hc * sizeof(half_t));
    for (int jb = 0; jb < HID; jb += Hc) {
      int hc = (HID - jb) < Hc ? (HID - jb) : Hc;
      k_gemm1_b<<<dim3(hc / 128, PADMAX / 128), 256, 0, stream>>>(
          xh, W1, b1, pair_tok, pad_off, ptotal, hbuf, jb, hc);
      k_gemm2_b<<<dim3(DIM / 128, PADMAX / 128), 256, 0, stream>>>(
          hbuf, W2, pair_tok, pair_wt, pad_off, ptotal, out, jb, hc);
    }
  }
}

// Round 4
// 626.274 us; speedup vs baseline: 1.2494x; 1.1949x over previous
//
#include <hip/hip_runtime.h>
#include <cstdint>
#include <cstddef>

// Problem constants (B=2,S=2048 -> T=4096; D=1024; H=4096; E=8; top-k=2)
#define T_TOK 4096
#define DIM   1024
#define HID   4096
#define NE    8
#define PAD   128
#define PADMAX 9216   // sum_e ceil(cnt_e/128)*128 <= 8192 + 8*127 = 9208 -> 9216
#define KSPLIT2 2     // split-K factor for GEMM2 (epilogue is atomic -> partials free)

typedef _Float16 half_t;
typedef __attribute__((ext_vector_type(8))) _Float16 half8;
typedef __attribute__((ext_vector_type(4))) float floatx4;

__device__ __forceinline__ float silu_f(float v) {
  return v / (1.0f + expf(-v));
}

__device__ __forceinline__ half8 cvt44(float4 a, float4 b) {
  half8 o;
  o[0] = (half_t)a.x; o[1] = (half_t)a.y; o[2] = (half_t)a.z; o[3] = (half_t)a.w;
  o[4] = (half_t)b.x; o[5] = (half_t)b.y; o[6] = (half_t)b.z; o[7] = (half_t)b.w;
  return o;
}

// Async global->LDS, 16B per lane. LDS dest = wave-uniform base + lane*16B;
// global src addr is per-lane. Data guaranteed landed after __syncthreads()
// (compiler drains vmcnt(0) before s_barrier).
__device__ __forceinline__ void gload16(const void* g, void* l) {
  __builtin_amdgcn_global_load_lds(
      (const __attribute__((address_space(1))) unsigned int*)g,
      (__attribute__((address_space(3))) unsigned int*)l, 16, 0, 0);
}

// Bijective XCD swizzle (requires Nw % 8 == 0; all grids satisfy this).
__device__ __forceinline__ int xcd_swz(int lin, int Nw) {
  int q = Nw >> 3;
  return (lin & 7) * q + (lin >> 3);
}

// ---------------------------------------------------------------------------
// Tiled ("chunk-order") operand layout. A 128(frag-row) x 64(K) f16 tile is
// 16 chunks of 512 halfs (1 KB). Chunk m <-> staging wave w=m>>2, rsub=(m>>1)&1,
// khalf=m&1: row-group rg = 2*(m>>2)+((m>>1)&1). Position p2 = lane*8+j:
//   frag_row = rg*16 + (lane&15);  frag_k = khalf*32 + (lane>>4)*8 + j.
// This mirrors the GEMM LDS layout exactly, so staging one tile = 16
// contiguous 1 KB copies (wave w takes chunks 4w..4w+3) -> fully coalesced,
// L2-channel-striped reads (fixes the 8KB/2KB-stride channel hot-spotting).
// ---------------------------------------------------------------------------

// Shared write phase for the weight re-layout kernels.
// sT is [64][136] f16: sT[k_local][row_local].
__device__ __forceinline__ void write_tiled(const half_t* sT, half_t* dstTile, int tid) {
#pragma unroll
  for (int t2 = 0; t2 < 4; ++t2) {
    int o = (t2 * 256 + tid) * 8;
    int m = o >> 9, p2 = o & 511;
    int lane2 = p2 >> 3;
    int rg = ((m >> 2) << 1) | ((m >> 1) & 1);
    int khalf = m & 1;
    int fr = rg * 16 + (lane2 & 15);
    int fk = khalf * 32 + (lane2 >> 4) * 8;
    half8 v;
#pragma unroll
    for (int j = 0; j < 8; ++j) v[j] = sT[(fk + j) * 136 + fr];
    *(half8*)(dstTile + o) = v;
  }
}

// ---------------------------------------------------------------- reset
__global__ void k_reset(float* prob_sum, unsigned* cnt, unsigned* cursor,
                        int* pair_tok, float* pair_wt) {
  int i = blockIdx.x * 256 + threadIdx.x;
  if (i < PADMAX) { pair_tok[i] = 0; pair_wt[i] = 0.0f; }
  if (i < NE) { prob_sum[i] = 0.0f; cnt[i] = 0u; cursor[i] = 0u; }
}

// ---------------------------------------------------------------- x fp32 -> f16 (once)
__global__ __launch_bounds__(256) void k_cvt_x(const float* __restrict__ x,
                                               half_t* __restrict__ xh) {
  size_t i = (size_t)blockIdx.x * 256 + threadIdx.x;   // one half8 per thread
  const float4* s = (const float4*)(x + i * 8);
  float4 a = s[0], b = s[1];
  *(half8*)(xh + i * 8) = cvt44(a, b);
}

// ---------------- W1 [E][D][H] -> W1c tiled [E][Hc/128][DIM/64][8192] f16
// Tile (e,J,Kd): frag_row = h-local (J*128+), frag_k = d-local (Kd*64+).
__global__ __launch_bounds__(256) void k_tr_w1(const float* __restrict__ W1,
                                               half_t* __restrict__ W1c,
                                               int j0, int Hc) {
  __shared__ half_t sT[64 * 136];
  int e = blockIdx.z, J = blockIdx.x, Kd = blockIdx.y;
  int tid = threadIdx.x;
  {
    int rr = tid >> 2, q = tid & 3;   // rr = d-local row, q*32 = h-local cols
    const float* s = W1 + ((size_t)e * DIM + Kd * 64 + rr) * HID + j0 + J * 128 + q * 32;
    float4 f[8];
#pragma unroll
    for (int i = 0; i < 8; ++i) f[i] = ((const float4*)s)[i];
    half_t* d = sT + rr * 136 + q * 32;
#pragma unroll
    for (int i = 0; i < 4; ++i) *(half8*)(d + i * 8) = cvt44(f[2 * i], f[2 * i + 1]);
  }
  __syncthreads();
  half_t* dstTile = W1c + (((size_t)e * (Hc >> 7) + J) * (DIM / 64) + Kd) * 8192;
  write_tiled(sT, dstTile, tid);
}

// ---------------- W2 [E][H][D] -> W2c tiled [E][DIM/128][Hc/64][8192] f16
// Tile (e,J,K2): frag_row = d-local (J*128+), frag_k = h-local (K2*64+).
__global__ __launch_bounds__(256) void k_tr_w2(const float* __restrict__ W2,
                                               half_t* __restrict__ W2c,
                                               int j0, int Hc) {
  __shared__ half_t sT[64 * 136];
  int e = blockIdx.z, J = blockIdx.x, K2 = blockIdx.y;
  int tid = threadIdx.x;
  {
    int hh = tid >> 2, q = tid & 3;   // hh = h-local row, q*32 = d-local cols
    const float* s = W2 + ((size_t)e * HID + j0 + K2 * 64 + hh) * DIM + J * 128 + q * 32;
    float4 f[8];
#pragma unroll
    for (int i = 0; i < 8; ++i) f[i] = ((const float4*)s)[i];
    half_t* d = sT + hh * 136 + q * 32;
#pragma unroll
    for (int i = 0; i < 4; ++i) *(half8*)(d + i * 8) = cvt44(f[2 * i], f[2 * i + 1]);
  }
  __syncthreads();
  half_t* dstTile = W2c + (((size_t)e * (DIM / 128) + J) * (Hc >> 6) + K2) * 8192;
  write_tiled(sT, dstTile, tid);
}

// ---------------------------------------------------------------- router
__global__ __launch_bounds__(256) void k_router(
    const float* __restrict__ x, const float* __restrict__ Wg,
    int* __restrict__ top_i, float* __restrict__ top_w,
    float* __restrict__ prob_sum, unsigned* __restrict__ cnt) {
  __shared__ float sWg[NE * DIM];
  __shared__ float sProb[NE];
  __shared__ unsigned sCnt[NE];
  int tid = threadIdx.x;
  if (tid < NE) { sProb[tid] = 0.0f; sCnt[tid] = 0u; }
  for (int i = tid; i < NE * DIM; i += 256) sWg[i] = Wg[i];
  __syncthreads();

  int wave = tid >> 6, lane = tid & 63;
  for (int it = 0; it < 4; ++it) {
    int t = blockIdx.x * 16 + wave * 4 + it;
    const float* xp = x + (size_t)t * DIM;
    float acc[NE];
#pragma unroll
    for (int e = 0; e < NE; ++e) acc[e] = 0.0f;
    for (int i = 0; i < DIM / 64; ++i) {
      int d = i * 64 + lane;
      float xd = xp[d];
#pragma unroll
      for (int e = 0; e < NE; ++e) acc[e] = fmaf(xd, sWg[e * DIM + d], acc[e]);
    }
#pragma unroll
    for (int off = 32; off > 0; off >>= 1)
#pragma unroll
      for (int e = 0; e < NE; ++e) acc[e] += __shfl_xor(acc[e], off, 64);

    if (lane == 0) {
      float m = acc[0];
#pragma unroll
      for (int e = 1; e < NE; ++e) m = fmaxf(m, acc[e]);
      float pr[NE]; float s = 0.0f;
#pragma unroll
      for (int e = 0; e < NE; ++e) { pr[e] = expf(acc[e] - m); s += pr[e]; }
      float inv = 1.0f / s;
#pragma unroll
      for (int e = 0; e < NE; ++e) pr[e] *= inv;
      int i0 = 0; float v0 = pr[0];
#pragma unroll
      for (int e = 1; e < NE; ++e) if (pr[e] > v0) { v0 = pr[e]; i0 = e; }
      int i1 = -1; float v1 = -1.0f;
#pragma unroll
      for (int e = 0; e < NE; ++e) if (e != i0 && pr[e] > v1) { v1 = pr[e]; i1 = e; }
      float wn = 1.0f / (v0 + v1);
      top_i[t * 2 + 0] = i0; top_i[t * 2 + 1] = i1;
      top_w[t * 2 + 0] = v0 * wn; top_w[t * 2 + 1] = v1 * wn;
#pragma unroll
      for (int e = 0; e < NE; ++e) atomicAdd(&sProb[e], pr[e]);
      atomicAdd(&sCnt[i0], 1u);
      atomicAdd(&sCnt[i1], 1u);
    }
  }
  __syncthreads();
  if (tid < NE) {
    atomicAdd(&prob_sum[tid], sProb[tid]);
    atomicAdd(&cnt[tid], sCnt[tid]);
  }
}

// ---------------------------------------------------------------- scan + aux loss
__global__ void k_scan(const unsigned* __restrict__ cnt,
                       const float* __restrict__ prob_sum,
                       int* __restrict__ pad_off, int* __restrict__ ptotal,
                       float* __restrict__ aux_out) {
  if (threadIdx.x == 0 && blockIdx.x == 0) {
    int off = 0; float aux = 0.0f;
    for (int e = 0; e < NE; ++e) {
      pad_off[e] = off;
      off += (int)((cnt[e] + (PAD - 1u)) & ~(unsigned)(PAD - 1));
      aux += ((float)cnt[e] / (float)T_TOK) * (prob_sum[e] / (float)T_TOK);
    }
    pad_off[NE] = off;
    *ptotal = off;
    *aux_out = (float)NE * aux;
  }
}

// ---------------------------------------------------------------- scatter pairs
__global__ void k_scatter(const int* __restrict__ top_i, const float* __restrict__ top_w,
                          const int* __restrict__ pad_off, unsigned* __restrict__ cursor,
                          int* __restrict__ pair_tok, float* __restrict__ pair_wt) {
  int t = blockIdx.x * 256 + threadIdx.x;
  if (t >= T_TOK) return;
#pragma unroll
  for (int k = 0; k < 2; ++k) {
    int e = top_i[t * 2 + k];
    unsigned pos = atomicAdd(&cursor[e], 1u);
    int idx = pad_off[e] + (int)pos;
    pair_tok[idx] = t;
    pair_wt[idx]  = top_w[t * 2 + k];
  }
}

// ---------------------------------------------------------------- out = w0*b2[e0] + w1*b2[e1]
__global__ void k_init_out(const int* __restrict__ top_i, const float* __restrict__ top_w,
                           const float* __restrict__ b2, float* __restrict__ out) {
  int idx = blockIdx.x * 256 + threadIdx.x;
  int t = idx >> 10, d = idx & (DIM - 1);
  int e0 = top_i[t * 2 + 0], e1 = top_i[t * 2 + 1];
  out[idx] = top_w[t * 2 + 0] * b2[e0 * DIM + d] + top_w[t * 2 + 1] * b2[e1 * DIM + d];
}

// ================================================================ Mode A GEMM1
// A = xh (token gather, unchanged); B = W1c tiled (contiguous 1KB staging).
// Output written to hbuf in tiled (chunk-order) layout for GEMM2's A staging.
__global__ __launch_bounds__(256) void k_gemm1_a(
    const half_t* __restrict__ xh, const half_t* __restrict__ W1c,
    const float* __restrict__ b1, const int* __restrict__ pair_tok,
    const int* __restrict__ pad_off, const int* __restrict__ ptotal,
    half_t* __restrict__ hbuf, int j0, int Hc) {
  __shared__ half_t lds[16384];
  int wid = xcd_swz(blockIdx.x, gridDim.x);
  int col = wid / (PADMAX / 128);          // H-column tile
  int row = wid % (PADMAX / 128);          // token-pair row tile
  int P = *ptotal;
  int p0 = row * 128;
  if (p0 >= P) return;
  int e = 0;
#pragma unroll
  for (int q = 1; q < NE; ++q) if (p0 >= pad_off[q]) e = q;

  int tid = threadIdx.x, w = tid >> 6, l = tid & 63;
  int lr = l & 15, lq = l >> 4;
  int wr = w >> 1, wc = w & 1;
  int w4 = 4 * w;
  int jt = col * 128;

  int tok0 = pair_tok[p0 + (2 * w) * 16 + lr];
  int tok1 = pair_tok[p0 + (2 * w + 1) * 16 + lr];
  const half_t* gA0 = xh + (size_t)tok0 * DIM + lq * 8;
  const half_t* gA1 = xh + (size_t)tok1 * DIM + lq * 8;
  const half_t* gBt = W1c + (((size_t)e * (Hc >> 7) + (jt >> 7)) * (DIM / 64)) * 8192 + l * 8;

  half_t* ldsA = lds;
  half_t* ldsB = lds + 8192;
  half_t* dA = ldsA + w4 * 512;
  half_t* dB = ldsB + w4 * 512;

  floatx4 acc[4][4];
#pragma unroll
  for (int i = 0; i < 4; ++i)
#pragma unroll
    for (int j = 0; j < 4; ++j) acc[i][j] = (floatx4){0.f, 0.f, 0.f, 0.f};

  for (int s = 0; s < DIM / 64; ++s) {
    int kt = s * 64;
    __syncthreads();                       // previous iteration's reads done
    gload16(gA0 + kt,      dA + 0 * 512);
    gload16(gA0 + kt + 32, dA + 1 * 512);
    gload16(gA1 + kt,      dA + 2 * 512);
    gload16(gA1 + kt + 32, dA + 3 * 512);
    const half_t* gBs = gBt + (size_t)s * 8192;
#pragma unroll
    for (int i = 0; i < 4; ++i) gload16(gBs + (w4 + i) * 512, dB + i * 512);
    __syncthreads();                       // vmcnt(0) drain -> tiles landed
#pragma unroll
    for (int ks = 0; ks < 2; ++ks) {
      half8 a[4], b[4];
#pragma unroll
      for (int i = 0; i < 4; ++i)
        a[i] = *(const half8*)(ldsA + ((4 * wr + i) * 2 + ks) * 512 + l * 8);
#pragma unroll
      for (int j = 0; j < 4; ++j)
        b[j] = *(const half8*)(ldsB + ((4 * wc + j) * 2 + ks) * 512 + l * 8);
#pragma unroll
      for (int i = 0; i < 4; ++i)
#pragma unroll
        for (int j = 0; j < 4; ++j)
          acc[i][j] = __builtin_amdgcn_mfma_f32_16x16x32_f16(a[i], b[j], acc[i][j], 0, 0, 0);
    }
  }
  __syncthreads();

#pragma unroll
  for (int j = 0; j < 4; ++j) {
    int coll = (4 * wc + j) * 16 + lr;
    float bias = b1[(size_t)e * HID + j0 + jt + coll];
#pragma unroll
    for (int i = 0; i < 4; ++i)
#pragma unroll
      for (int r = 0; r < 4; ++r) {
        int row2 = (4 * wr + i) * 16 + lq * 4 + r;
        lds[row2 * 128 + coll] = (half_t)silu_f(acc[i][j][r] + bias);
      }
  }
  __syncthreads();
  // Tiled hbuf write: this block's 128x128 output = 2 chunk-order A-tiles
  // (k-tiles jt/64, jt/64+1) for GEMM2. 32 KB contiguous, coalesced.
  {
    size_t tb = ((size_t)(p0 >> 7) * (Hc >> 6) + (jt >> 6)) * 8192;
#pragma unroll
    for (int t2 = 0; t2 < 8; ++t2) {
      int o = (t2 * 256 + tid) * 8;
      int kk = o >> 13, rem = o & 8191;
      int m = rem >> 9, p2 = rem & 511;
      int lane2 = p2 >> 3;
      int rg = ((m >> 2) << 1) | ((m >> 1) & 1);
      int rr = rg * 16 + (lane2 & 15);
      int colb = kk * 64 + (m & 1) * 32 + (lane2 >> 4) * 8;
      *(half8*)(hbuf + tb + o) = *(const half8*)(lds + rr * 128 + colb);
    }
  }
}

// ================================================================ Mode A GEMM2
// A = hbuf tiled, B = W2c tiled -> all staging contiguous. Split-K by KSPLIT2.
__global__ __launch_bounds__(256) void k_gemm2_a(
    const half_t* __restrict__ hbuf, const half_t* __restrict__ W2c,
    const int* __restrict__ pair_tok, const float* __restrict__ pair_wt,
    const int* __restrict__ pad_off, const int* __restrict__ ptotal,
    float* __restrict__ out, int Hc) {
  __shared__ half_t lds[16384];
  int wid = xcd_swz(blockIdx.x, gridDim.x);
  int c  = wid & 7;                 // D-column tile (DIM/128 = 8)
  int rz = wid >> 3;
  int row = rz % (PADMAX / 128);    // token-pair row tile
  int zk  = rz / (PADMAX / 128);    // K-split index
  int P = *ptotal;
  int p0 = row * 128;
  if (p0 >= P) return;
  int e = 0;
#pragma unroll
  for (int q = 1; q < NE; ++q) if (p0 >= pad_off[q]) e = q;

  int tid = threadIdx.x, w = tid >> 6, l = tid & 63;
  int lr = l & 15, lq = l >> 4;
  int wr = w >> 1, wc = w & 1;
  int w4 = 4 * w;
  int jt = c * 128;

  int nkt = Hc >> 6;                       // K-tiles total
  int t_beg = (zk * nkt) / KSPLIT2;
  int t_end = ((zk + 1) * nkt) / KSPLIT2;

  const half_t* gA = hbuf + ((size_t)row * nkt) * 8192 + l * 8;
  const half_t* gB = W2c + (((size_t)e * (DIM / 128) + c) * nkt) * 8192 + l * 8;

  half_t* ldsA = lds;
  half_t* ldsB = lds + 8192;
  half_t* dA = ldsA + w4 * 512;
  half_t* dB = ldsB + w4 * 512;

  floatx4 acc[4][4];
#pragma unroll
  for (int i = 0; i < 4; ++i)
#pragma unroll
    for (int j = 0; j < 4; ++j) acc[i][j] = (floatx4){0.f, 0.f, 0.f, 0.f};

  for (int s = t_beg; s < t_end; ++s) {
    const half_t* gAs = gA + (size_t)s * 8192;
    const half_t* gBs = gB + (size_t)s * 8192;
    __syncthreads();
#pragma unroll
    for (int i = 0; i < 4; ++i) gload16(gAs + (w4 + i) * 512, dA + i * 512);
#pragma unroll
    for (int i = 0; i < 4; ++i) gload16(gBs + (w4 + i) * 512, dB + i * 512);
    __syncthreads();
#pragma unroll
    for (int ks = 0; ks < 2; ++ks) {
      half8 a[4], b[4];
#pragma unroll
      for (int i = 0; i < 4; ++i)
        a[i] = *(const half8*)(ldsA + ((4 * wr + i) * 2 + ks) * 512 + l * 8);
#pragma unroll
      for (int j = 0; j < 4; ++j)
        b[j] = *(const half8*)(ldsB + ((4 * wc + j) * 2 + ks) * 512 + l * 8);
#pragma unroll
      for (int i = 0; i < 4; ++i)
#pragma unroll
        for (int j = 0; j < 4; ++j)
          acc[i][j] = __builtin_amdgcn_mfma_f32_16x16x32_f16(a[i], b[j], acc[i][j], 0, 0, 0);
    }
  }

#pragma unroll
  for (int i = 0; i < 4; ++i)
#pragma unroll
    for (int r = 0; r < 4; ++r) {
      int row2 = (4 * wr + i) * 16 + lq * 4 + r;
      float wt = pair_wt[p0 + row2];
      if (wt != 0.0f) {
        int tok = pair_tok[p0 + row2];
        float* op = out + (size_t)tok * DIM + jt;
#pragma unroll
        for (int j = 0; j < 4; ++j) {
          int coll = (4 * wc + j) * 16 + lr;
          unsafeAtomicAdd(op + coll, wt * acc[i][j][r]);
        }
      }
    }
}

// ================================================================ Mode B GEMM1 (fp32 W1 direct, A from xh)
__global__ __launch_bounds__(256) void k_gemm1_b(
    const half_t* __restrict__ xh, const float* __restrict__ W1,
    const float* __restrict__ b1, const int* __restrict__ pair_tok,
    const int* __restrict__ pad_off, const int* __restrict__ ptotal,
    half_t* __restrict__ hout, int j0, int Hc) {
  __shared__ half_t lds[16384];
  int P = *ptotal;
  int p0 = blockIdx.y * 128;
  if (p0 >= P) return;
  int e = 0;
#pragma unroll
  for (int q = 1; q < NE; ++q) if (p0 >= pad_off[q]) e = q;

  int tid = threadIdx.x, w = tid >> 6, l = tid & 63;
  int lr = l & 15, lq = l >> 4;
  int wr = w >> 1, wc = w & 1;
  int jt = blockIdx.x * 128;

  int tok0 = pair_tok[p0 + (2 * w) * 16 + lr];
  int tok1 = pair_tok[p0 + (2 * w + 1) * 16 + lr];
  const half_t* gA0 = xh + (size_t)tok0 * DIM + lq * 8;
  const half_t* gA1 = xh + (size_t)tok1 * DIM + lq * 8;
  const float* gBb = W1 + (size_t)e * DIM * HID + j0 + jt;
  const float* gB0 = gBb + (2 * w) * 16 + lr;
  const float* gB1 = gBb + (2 * w + 1) * 16 + lr;

  half_t* ldsA = lds;
  half_t* ldsB = lds + 8192;

  floatx4 acc[4][4];
#pragma unroll
  for (int i = 0; i < 4; ++i)
#pragma unroll
    for (int j = 0; j < 4; ++j) acc[i][j] = (floatx4){0.f, 0.f, 0.f, 0.f};

  for (int kt = 0; kt < DIM; kt += 64) {
    half8 va0 = *(const half8*)(gA0 + kt);
    half8 va1 = *(const half8*)(gA0 + kt + 32);
    half8 va2 = *(const half8*)(gA1 + kt);
    half8 va3 = *(const half8*)(gA1 + kt + 32);
    half8 vb[4];
#pragma unroll
    for (int fg = 0; fg < 4; ++fg) {
      const float* gb = (fg >> 1) ? gB1 : gB0;
      int kbase = kt + (fg & 1) * 32 + lq * 8;
#pragma unroll
      for (int j = 0; j < 8; ++j)
        vb[fg][j] = (half_t)gb[(size_t)(kbase + j) * HID];
    }
    __syncthreads();
    *(half8*)(ldsA + (4 * w + 0) * 512 + l * 8) = va0;
    *(half8*)(ldsA + (4 * w + 1) * 512 + l * 8) = va1;
    *(half8*)(ldsA + (4 * w + 2) * 512 + l * 8) = va2;
    *(half8*)(ldsA + (4 * w + 3) * 512 + l * 8) = va3;
    *(half8*)(ldsB + (4 * w + 0) * 512 + l * 8) = vb[0];
    *(half8*)(ldsB + (4 * w + 1) * 512 + l * 8) = vb[1];
    *(half8*)(ldsB + (4 * w + 2) * 512 + l * 8) = vb[2];
    *(half8*)(ldsB + (4 * w + 3) * 512 + l * 8) = vb[3];
    __syncthreads();
#pragma unroll
    for (int ks = 0; ks < 2; ++ks) {
      half8 a[4], b[4];
#pragma unroll
      for (int i = 0; i < 4; ++i)
        a[i] = *(const half8*)(ldsA + ((4 * wr + i) * 2 + ks) * 512 + l * 8);
#pragma unroll
      for (int j = 0; j < 4; ++j)
        b[j] = *(const half8*)(ldsB + ((4 * wc + j) * 2 + ks) * 512 + l * 8);
#pragma unroll
      for (int i = 0; i < 4; ++i)
#pragma unroll
        for (int j = 0; j < 4; ++j)
          acc[i][j] = __builtin_amdgcn_mfma_f32_16x16x32_f16(a[i], b[j], acc[i][j], 0, 0, 0);
    }
  }
  __syncthreads();

#pragma unroll
  for (int j = 0; j < 4; ++j) {
    int coll = (4 * wc + j) * 16 + lr;
    float bias = b1[(size_t)e * HID + j0 + jt + coll];
#pragma unroll
    for (int i = 0; i < 4; ++i)
#pragma unroll
      for (int r = 0; r < 4; ++r) {
        int row = (4 * wr + i) * 16 + lq * 4 + r;
        lds[row * 128 + coll] = (half_t)silu_f(acc[i][j][r] + bias);
      }
  }
  __syncthreads();
#pragma unroll
  for (int ps = 0; ps < 4; ++ps) {
    int r = ps * 32 + (tid >> 3), c = (tid & 7) * 16;
    half8 v0 = *(const half8*)(lds + r * 128 + c);
    half8 v1 = *(const half8*)(lds + r * 128 + c + 8);
    half_t* dst = hout + (size_t)(p0 + r) * Hc + jt + c;
    *(half8*)dst = v0;
    *(half8*)(dst + 8) = v1;
  }
}

// ================================================================ Mode B GEMM2 (fp32 W2 direct)
__global__ __launch_bounds__(256) void k_gemm2_b(
    const half_t* __restrict__ hbuf, const float* __restrict__ W2,
    const int* __restrict__ pair_tok, const float* __restrict__ pair_wt,
    const int* __restrict__ pad_off, const int* __restrict__ ptotal,
    float* __restrict__ out, int j0, int Hc) {
  __shared__ half_t lds[16384];
  int P = *ptotal;
  int p0 = blockIdx.y * 128;
  if (p0 >= P) return;
  int e = 0;
#pragma unroll
  for (int q = 1; q < NE; ++q) if (p0 >= pad_off[q]) e = q;

  int tid = threadIdx.x, w = tid >> 6, l = tid & 63;
  int lr = l & 15, lq = l >> 4;
  int wr = w >> 1, wc = w & 1;
  int jt = blockIdx.x * 128;

  const half_t* gA0 = hbuf + (size_t)(p0 + (2 * w) * 16 + lr) * Hc + lq * 8;
  const half_t* gA1 = hbuf + (size_t)(p0 + (2 * w + 1) * 16 + lr) * Hc + lq * 8;
  const float* gBb = W2 + (size_t)e * HID * DIM + jt;
  const float* gB0 = gBb + (2 * w) * 16 + lr;
  const float* gB1 = gBb + (2 * w + 1) * 16 + lr;

  half_t* ldsA = lds;
  half_t* ldsB = lds + 8192;

  floatx4 acc[4][4];
#pragma unroll
  for (int i = 0; i < 4; ++i)
#pragma unroll
    for (int j = 0; j < 4; ++j) acc[i][j] = (floatx4){0.f, 0.f, 0.f, 0.f};

  for (int kt = 0; kt < Hc; kt += 64) {
    half8 va0 = *(const half8*)(gA0 + kt);
    half8 va1 = *(const half8*)(gA0 + kt + 32);
    half8 va2 = *(const half8*)(gA1 + kt);
    half8 va3 = *(const half8*)(gA1 + kt + 32);
    half8 vb[4];
#pragma unroll
    for (int fg = 0; fg < 4; ++fg) {
      const float* gb = (fg >> 1) ? gB1 : gB0;
      int kbase = j0 + kt + (fg & 1) * 32 + lq * 8;
#pragma unroll
      for (int j = 0; j < 8; ++j)
        vb[fg][j] = (half_t)gb[(size_t)(kbase + j) * DIM];
    }
    __syncthreads();
    *(half8*)(ldsA + (4 * w + 0) * 512 + l * 8) = va0;
    *(half8*)(ldsA + (4 * w + 1) * 512 + l * 8) = va1;
    *(half8*)(ldsA + (4 * w + 2) * 512 + l * 8) = va2;
    *(half8*)(ldsA + (4 * w + 3) * 512 + l * 8) = va3;
    *(half8*)(ldsB + (4 * w + 0) * 512 + l * 8) = vb[0];
    *(half8*)(ldsB + (4 * w + 1) * 512 + l * 8) = vb[1];
    *(half8*)(ldsB + (4 * w + 2) * 512 + l * 8) = vb[2];
    *(half8*)(ldsB + (4 * w + 3) * 512 + l * 8) = vb[3];
    __syncthreads();
#pragma unroll
    for (int ks = 0; ks < 2; ++ks) {
      half8 a[4], b[4];
#pragma unroll
      for (int i = 0; i < 4; ++i)
        a[i] = *(const half8*)(ldsA + ((4 * wr + i) * 2 + ks) * 512 + l * 8);
#pragma unroll
      for (int j = 0; j < 4; ++j)
        b[j] = *(const half8*)(ldsB + ((4 * wc + j) * 2 + ks) * 512 + l * 8);
#pragma unroll
      for (int i = 0; i < 4; ++i)
#pragma unroll
        for (int j = 0; j < 4; ++j)
          acc[i][j] = __builtin_amdgcn_mfma_f32_16x16x32_f16(a[i], b[j], acc[i][j], 0, 0, 0);
    }
  }

#pragma unroll
  for (int i = 0; i < 4; ++i)
#pragma unroll
    for (int r = 0; r < 4; ++r) {
      int row = (4 * wr + i) * 16 + lq * 4 + r;
      float wt = pair_wt[p0 + row];
      if (wt != 0.0f) {
        int tok = pair_tok[p0 + row];
        float* op = out + (size_t)tok * DIM + jt;
#pragma unroll
        for (int j = 0; j < 4; ++j) {
          int coll = (4 * wc + j) * 16 + lr;
          unsafeAtomicAdd(op + coll, wt * acc[i][j][r]);
        }
      }
    }
}

// ---------------------------------------------------------------- launch
extern "C" void kernel_launch(void* const* d_in, const int* in_sizes, int n_in,
                              void* d_out, int out_size, void* d_ws, size_t ws_size,
                              hipStream_t stream) {
  const float* x  = (const float*)d_in[0];
  const float* Wg = (const float*)d_in[1];
  const float* W1 = (const float*)d_in[2];
  const float* b1 = (const float*)d_in[3];
  const float* W2 = (const float*)d_in[4];
  const float* b2 = (const float*)d_in[5];
  float* out = (float*)d_out;

  char* p = (char*)d_ws;
  auto alloc = [&](size_t bytes) -> char* {
    char* r = p; p += (bytes + 255) & ~(size_t)255; return r;
  };
  int*      top_i    = (int*)     alloc((size_t)T_TOK * 2 * sizeof(int));
  float*    top_w    = (float*)   alloc((size_t)T_TOK * 2 * sizeof(float));
  float*    prob_sum = (float*)   alloc(NE * sizeof(float));
  unsigned* cnt      = (unsigned*)alloc(NE * sizeof(unsigned));
  int*      pad_off  = (int*)     alloc((NE + 1) * sizeof(int));
  int*      ptotal   = (int*)     alloc(sizeof(int));
  unsigned* cursor   = (unsigned*)alloc(NE * sizeof(unsigned));
  int*      pair_tok = (int*)     alloc(PADMAX * sizeof(int));
  float*    pair_wt  = (float*)   alloc(PADMAX * sizeof(float));
  half_t*   xh       = (half_t*)  alloc((size_t)T_TOK * DIM * sizeof(half_t)); // 8 MB

  size_t used  = (size_t)(p - (char*)d_ws);
  size_t avail = ws_size > used ? ws_size - used : 0;

  // Mode A per-H-column cost: W1c + W2c (2*NE*DIM*2B) + hbuf (PADMAX*2B) = 51200 B
  size_t per_col_a = (size_t)2 * NE * DIM * sizeof(half_t) + (size_t)PADMAX * sizeof(half_t);
  int HcA = (int)((avail / per_col_a) & ~(size_t)127);
  if (HcA > HID) HcA = HID;
  bool modeA = (HcA >= 128);

  k_reset<<<dim3((PADMAX + 255) / 256), 256, 0, stream>>>(prob_sum, cnt, cursor, pair_tok, pair_wt);
  k_cvt_x<<<dim3((size_t)T_TOK * DIM / 8 / 256), 256, 0, stream>>>(x, xh);
  k_router<<<dim3(T_TOK / 16), 256, 0, stream>>>(x, Wg, top_i, top_w, prob_sum, cnt);
  k_scan<<<1, 64, 0, stream>>>(cnt, prob_sum, pad_off, ptotal, out + (size_t)T_TOK * DIM);
  k_scatter<<<dim3(T_TOK / 256), 256, 0, stream>>>(top_i, top_w, pad_off, cursor, pair_tok, pair_wt);
  k_init_out<<<dim3((size_t)T_TOK * DIM / 256), 256, 0, stream>>>(top_i, top_w, b2, out);

  if (modeA) {
    int Hc = HcA;
    half_t* W1c  = (half_t*)alloc((size_t)NE * Hc * DIM * sizeof(half_t));
    half_t* W2c  = (half_t*)alloc((size_t)NE * DIM * Hc * sizeof(half_t));
    half_t* hbuf = (half_t*)alloc((size_t)PADMAX * Hc * sizeof(half_t));
    for (int jb = 0; jb < HID; jb += Hc) {
      int hc = (HID - jb) < Hc ? (HID - jb) : Hc;   // multiple of 128
      k_tr_w1<<<dim3(hc / 128, DIM / 64, NE), 256, 0, stream>>>(W1, W1c, jb, hc);
      // 1D swizzled grid: (hc/128) cols x 72 rows; 72 = 8*9 keeps Nw % 8 == 0
      k_gemm1_a<<<dim3((hc / 128) * (PADMAX / 128)), 256, 0, stream>>>(
          xh, W1c, b1, pair_tok, pad_off, ptotal, hbuf, jb, hc);
      k_tr_w2<<<dim3(DIM / 128, hc / 64, NE), 256, 0, stream>>>(W2, W2c, jb, hc);
      // 1D swizzled grid: 8 cols x 72 rows x KSPLIT2 = 1152 blocks
      k_gemm2_a<<<dim3((DIM / 128) * (PADMAX / 128) * KSPLIT2), 256, 0, stream>>>(
          hbuf, W2c, pair_tok, pair_wt, pad_off, ptotal, out, hc);
    }
  } else {
    // Mode B: only hbuf (row-major), fp32 weights read directly in the GEMMs.
    int Hc = (int)((avail / ((size_t)PADMAX * sizeof(half_t))) & ~(size_t)127);
    if (Hc > HID) Hc = HID;
    if (Hc < 128) Hc = 128;
    half_t* hbuf = (half_t*)alloc((size_t)PADMAX * Hc * sizeof(half_t));
    for (int jb = 0; jb < HID; jb += Hc) {
      int hc = (HID - jb) < Hc ? (HID - jb) : Hc;
      k_gemm1_b<<<dim3(hc / 128, PADMAX / 128), 256, 0, stream>>>(
          xh, W1, b1, pair_tok, pad_off, ptotal, hbuf, jb, hc);
      k_gemm2_b<<<dim3(DIM / 128, PADMAX / 128), 256, 0, stream>>>(
          hbuf, W2, pair_tok, pair_wt, pad_off, ptotal, out, jb, hc);
    }
  }
}